// Round 12
// baseline (429.089 us; speedup 1.0000x reference)
//
#include <hip/hip_runtime.h>
#include <stdint.h>
#include <math.h>

// ---------------- problem constants ----------------
static constexpr int NN = 160000;   // nodes
static constexpr int NE = 640000;   // edges
static constexpr int NG = 8000;     // graphs (20 nodes each, contiguous)
static constexpr int FH  = 63;      // hidden
static constexpr int ZST = 64;      // bf16 elems per Z row (128 B)
static constexpr int FST = 80;      // bf16 elems per feats row (160 B)
static constexpr int NB  = 128;     // nodes per block (8 waves x 8 x 2 iters)
static constexpr int LGRID = 1536;  // >= sum_k ceil(cnt_k/NB) <= ~1260

// ---------------- workspace layout (bytes) ----------------
static constexpr size_t OFF_DEGCNT = 0;                       // 160000 i32
static constexpr size_t OFF_CURSOR = 640000;                  // 160000 i32
static constexpr size_t OFF_BCNT   = 1280000;                 // 16 i32 (10 bcnt + ctrs)
static constexpr size_t OFF_SPART  = 1280064;                 // 3*256*128 f32
static constexpr size_t ZERO_BYTES = 1673280;                 // everything above zeroed
static constexpr size_t OFF_ROWPTR = 1673280;                 // 160001 i32
static constexpr size_t OFF_BLKSUM = 2313472;                 // 512 i32
static constexpr size_t OFF_COL    = 2315520;                 // 640000 i32
static constexpr size_t OFF_BLIST  = 4875520;                 // 10*160000 int2 (n, row_start)
static constexpr size_t OFF_AFC    = 17675520;                // 3*2*64 f32
static constexpr size_t OFF_BNG2   = 17709312;                // 128 f32
static constexpr size_t OFF_PBLK   = 17709824;                // 11 i32
static constexpr size_t OFF_FB     = 17710080;                // 160000*80 bf16 (feats cast)
static constexpr size_t OFF_Z0     = 43310080;                // 160000*64 bf16
static constexpr size_t OFF_Z1     = 63790080;                // 160000*64 bf16 (free after layer2)
// Z1 region reused after layer2 for the readout weight fragments:
static constexpr size_t OFF_WNGF   = OFF_Z1;                  // 4*8*64*8 bf16 = 32 KB
static constexpr size_t OFF_WTRF   = OFF_Z1 + 32768;          // 16*8*64*8 bf16 = 128 KB
// total ~84.3 MB

// ---------------- bf16 helpers ----------------
__device__ __forceinline__ float blo(unsigned u) {
    union { unsigned i; float f; } v; v.i = u << 16; return v.f;
}
__device__ __forceinline__ float bhi(unsigned u) {
    union { unsigned i; float f; } v; v.i = u & 0xffff0000u; return v.f;
}
__device__ __forceinline__ unsigned short f2b(float f) {
    union { float f; unsigned i; } v; v.f = f;
    unsigned r = v.i + 0x7fffu + ((v.i >> 16) & 1u);
    return (unsigned short)(r >> 16);
}
// accumulate 8 bf16 (one uint4) into 8 f32
__device__ __forceinline__ void acc8(float* a, uint4 q) {
    a[0] += blo(q.x); a[1] += bhi(q.x);
    a[2] += blo(q.y); a[3] += bhi(q.y);
    a[4] += blo(q.z); a[5] += bhi(q.z);
    a[6] += blo(q.w); a[7] += bhi(q.w);
}

// ---------------- MFMA types ----------------
typedef __attribute__((ext_vector_type(8))) short bf16x8;
typedef __attribute__((ext_vector_type(4))) float f32x4;
union U8 { uint4 u; bf16x8 b; };

// ---------------- fused cast + degree ----------------
// feats f32 [NN][74] -> bf16 [NN][80] (padded with zeros); first NE threads
// also do the degree histogram (independent work, saves a serial launch).
__global__ void k_cast(const float* __restrict__ feats, unsigned short* __restrict__ fb,
                       const int* __restrict__ dst, int* __restrict__ degcnt) {
    int i = blockIdx.x * 256 + threadIdx.x;
    if (i < NE) atomicAdd(&degcnt[dst[i]], 1);
    if (i >= NN * FST) return;
    int n = i / FST, c = i - n * FST;
    float v = (c < 74) ? feats[n * 74 + c] : 0.f;
    union { float f; unsigned u; } x; x.f = v;
    unsigned r = x.u + 0x7fffu + ((x.u >> 16) & 1u);
    fb[i] = (unsigned short)(r >> 16);
}

__global__ void k_scan1(const int* __restrict__ degcnt, int* __restrict__ row_ptr,
                        int* __restrict__ blksum) {
    __shared__ int s[1024];
    int t = threadIdx.x;
    int i = blockIdx.x * 1024 + t;
    int v = (i < NN) ? degcnt[i] : 0;
    s[t] = v; __syncthreads();
    for (int off = 1; off < 1024; off <<= 1) {
        int x = (t >= off) ? s[t - off] : 0;
        __syncthreads();
        s[t] += x;
        __syncthreads();
    }
    if (i < NN) row_ptr[i + 1] = s[t];
    if (t == 1023) blksum[blockIdx.x] = s[t];
}

__global__ void k_scan2(int* __restrict__ blksum, int nblk) {
    __shared__ int s[256];
    int t = threadIdx.x;
    int v = (t < nblk) ? blksum[t] : 0;
    s[t] = v; __syncthreads();
    for (int off = 1; off < 256; off <<= 1) {
        int x = (t >= off) ? s[t - off] : 0;
        __syncthreads();
        s[t] += x;
        __syncthreads();
    }
    if (t < nblk) blksum[t] = s[t] - v;
}

__global__ void k_scan3(int* __restrict__ row_ptr, const int* __restrict__ blksum) {
    int t = threadIdx.x;
    int i = blockIdx.x * 1024 + t;
    if (i < NN) row_ptr[i + 1] += blksum[blockIdx.x];
    if (i == 0) row_ptr[0] = 0;
}

// LDS-aggregated bucket build; stores (node, row_start). Last-finishing block
// also computes pblk (folds the old k_prep launch; cold kernel, fence is cheap
// here — R16's mistake was putting this pattern in the HOT kernel).
__global__ void __launch_bounds__(1024) k_bucket(
        const int* __restrict__ degcnt, const int* __restrict__ row_ptr,
        int* __restrict__ bcnt, int2* __restrict__ blist,
        int* __restrict__ pblk, int* __restrict__ ctr) {
    __shared__ int scnt[10], sbase[10];
    __shared__ int sLast;
    int tid = threadIdx.x;
    if (tid < 10) scnt[tid] = 0;
    __syncthreads();
    int n = blockIdx.x * 1024 + tid;
    int k = 0, pos = 0;
    bool v = (n < NN);
    int rp = 0;
    if (v) {
        int d = degcnt[n];
        rp = row_ptr[n];
        k = (d < 1) ? 0 : ((d > 10) ? 9 : d - 1);
        pos = atomicAdd(&scnt[k], 1);
    }
    __syncthreads();
    if (tid < 10) sbase[tid] = scnt[tid] ? atomicAdd(&bcnt[tid], scnt[tid]) : 0;
    __syncthreads();
    if (v) blist[k * NN + sbase[k] + pos] = make_int2(n, rp);

    // last-block-done: compute pblk
    if (tid == 0) {
        __threadfence();
        sLast = (atomicAdd(ctr, 1) == (int)gridDim.x - 1) ? 1 : 0;
    }
    __syncthreads();
    if (sLast && tid == 0) {
        __threadfence();
        const volatile int* bc = bcnt;
        int s = 0; pblk[0] = 0;
        for (int kk = 0; kk < 10; ++kk) { s += (bc[kk] + NB - 1) / NB; pblk[kk + 1] = s; }
    }
}

__global__ void k_fill(const int* __restrict__ src, const int* __restrict__ dst,
                       const int* __restrict__ row_ptr, int* __restrict__ cursor,
                       int* __restrict__ col) {
    int e = blockIdx.x * 256 + threadIdx.x;
    if (e >= NE) return;
    int d = dst[e];
    int pos = row_ptr[d] + atomicAdd(&cursor[d], 1);
    col[pos] = src[e];
}

// ---------------- NF layer: asm-burst gather, 128 nodes/block, 8 waves ----------------
// R19 (cond ladder) spilled; R20 (clamped burst) compiled at VGPR=40 — the
// allocator re-serialized the 10-load burst into ~4 groups, each an exposed
// ~900cy wait (per-wave VALU fraction ~10% proves ~3400cy stall/iter). R21
// (this): FORCE the burst with one inline-asm block — 8x global_load_dwordx4
// (self + nb 0..6) back-to-back + s_waitcnt vmcnt(0) inside, "=&v" early-
// clobber so payload tuples can't alias address pairs. One exposed wait for
// deg<=7 (~95% of nodes); 2-load second burst for d7/d8 (buckets 7..8,
// wave-uniform). Addresses via R11's clamped cc[] (dup loads -> L1 hits).
// Accumulation order self->ascending unchanged: bit-identical FP.
// Tripwires: VGPR <= 85 (6 waves/SIMD, matches 3-block LDS cap), WRITE ~21MB.
// Bucket 9 (deg>=10, 0.8%) keeps the dynamic path.
template<int FI, int IST, bool AFF>
__global__ void __launch_bounds__(512, 4) k_layer(
    const unsigned short* __restrict__ in,
    const float* __restrict__ aff,
    const int* __restrict__ row_ptr, const int* __restrict__ col,
    const int* __restrict__ bcnt, const int2* __restrict__ blist,
    const int* __restrict__ pblk,
    const float* __restrict__ W, const float* __restrict__ B,
    unsigned short* __restrict__ zout, float* __restrict__ spart)
{
    constexpr int CH = IST / 8;      // uint4 chunks per row (64->8, 80->10)
    __shared__ float sW[FI * 63 + 64];
    __shared__ float sTot[8][IST][8];
    __shared__ int   sN[8][8];
    __shared__ float sRed[2][8][64];

    int b = blockIdx.x;
    if (b >= pblk[10]) return;
    int k = 0;
#pragma unroll
    for (int i = 1; i <= 9; ++i) k += (b >= pblk[i]) ? 1 : 0;   // uniform (sgpr)
    int base = (b - pblk[k]) * NB;
    int cnt = bcnt[k];
    if (base >= cnt) return;

    int tid = threadIdx.x;
    int wave = tid >> 6, lane = tid & 63;
    int t = lane >> 3, r = lane & 7;

    const float* Wk = W + (size_t)k * FI * 63;
#pragma unroll 4
    for (int i = tid; i < FI * 63; i += 512) sW[i] = Wk[i];
    __syncthreads();

    const uint4* inq = (const uint4*)in;
    float bterm = (lane < 63) ? B[k * 63 + lane] : 0.f;
    float lsum = 0.f, lsq = 0.f;

#pragma unroll 1
    for (int it = 0; it < NB / 64; ++it) {
        int idx = base + it * 64 + wave * 8 + t;
        if (base + it * 64 >= cnt) break;                 // whole-batch empty (uniform)
        bool val = (idx < cnt);
        int2 bl = blist[k * NN + (val ? idx : (cnt - 1))];
        int n = bl.x, rs = bl.y;
        // buckets 1..8: deg == k+1 exactly (uniform). 0 and 9: per-node.
        int dg = (k >= 1 && k <= 8) ? (k + 1) : (row_ptr[n + 1] - rs);
        if (r == 0) sN[wave][t] = val ? n : -1;

        float a[8] = {0.f, 0.f, 0.f, 0.f, 0.f, 0.f, 0.f, 0.f};

        if (k == 9) {
            // ---------- dynamic path (deg >= 10, ~0.8% of nodes) ----------
            {
                uint4 q = inq[(size_t)n * CH + r];
                acc8(a, q);
            }
            int d = 0;
#pragma unroll 1
            for (; d + 4 <= dg; d += 4) {
                int c0 = col[rs + d], c1 = col[rs + d + 1];
                int c2 = col[rs + d + 2], c3 = col[rs + d + 3];
                uint4 q0 = inq[(size_t)c0 * CH + r];
                uint4 q1 = inq[(size_t)c1 * CH + r];
                uint4 q2 = inq[(size_t)c2 * CH + r];
                uint4 q3 = inq[(size_t)c3 * CH + r];
                acc8(a, q0); acc8(a, q1); acc8(a, q2); acc8(a, q3);
            }
#pragma unroll 1
            for (; d < dg; ++d) {
                int c = col[rs + d];
                uint4 q = inq[(size_t)c * CH + r];
                acc8(a, q);
            }
            if constexpr (IST == 80) {
                float e2[8] = {0.f, 0.f, 0.f, 0.f, 0.f, 0.f, 0.f, 0.f};
                if (r < 2) {
                    uint4 q = inq[(size_t)n * CH + 8 + r];
                    acc8(e2, q);
                    int d2 = 0;
#pragma unroll 1
                    for (; d2 < dg; ++d2) {
                        int c = col[rs + d2];
                        uint4 p = inq[(size_t)c * CH + 8 + r];
                        acc8(e2, p);
                    }
#pragma unroll
                    for (int j = 0; j < 8; ++j) sTot[wave][64 + 8 * r + j][t] = e2[j];
                }
            }
        } else {
            // ---------- asm-burst gather (deg <= 9) ----------
            int dm1 = (dg > 0) ? (dg - 1) : 0;
            int cc[9];
#pragma unroll
            for (int d = 0; d < 9; ++d) {
                int off = (d < dg) ? d : dm1;
                int ic = rs + off;
                ic = (ic < NE) ? ic : (NE - 1);
                cc[d] = col[ic];
            }

            // L0 extra chunks first (r<2): compiler-scheduled, disjoint regs.
            if constexpr (IST == 80) {
                if (r < 2) {
                    float e2[8] = {0.f, 0.f, 0.f, 0.f, 0.f, 0.f, 0.f, 0.f};
                    uint4 ps = inq[(size_t)n * CH + 8 + r];
                    uint4 p0 = inq[(size_t)cc[0] * CH + 8 + r];
                    uint4 p1 = inq[(size_t)cc[1] * CH + 8 + r];
                    uint4 p2 = inq[(size_t)cc[2] * CH + 8 + r];
                    uint4 p3 = inq[(size_t)cc[3] * CH + 8 + r];
                    uint4 p4 = inq[(size_t)cc[4] * CH + 8 + r];
                    uint4 p5 = inq[(size_t)cc[5] * CH + 8 + r];
                    uint4 p6 = inq[(size_t)cc[6] * CH + 8 + r];
                    uint4 p7 = inq[(size_t)cc[7] * CH + 8 + r];
                    uint4 p8 = inq[(size_t)cc[8] * CH + 8 + r];
                    acc8(e2, ps);
                    if (dg > 0) acc8(e2, p0);
                    if (dg > 1) acc8(e2, p1);
                    if (dg > 2) acc8(e2, p2);
                    if (dg > 3) acc8(e2, p3);
                    if (dg > 4) acc8(e2, p4);
                    if (dg > 5) acc8(e2, p5);
                    if (dg > 6) acc8(e2, p6);
                    if (dg > 7) acc8(e2, p7);
                    if (dg > 8) acc8(e2, p8);
#pragma unroll
                    for (int j = 0; j < 8; ++j) sTot[wave][64 + 8 * r + j][t] = e2[j];
                }
            }

            // burst 1: self + neighbors 0..6, ONE exposed wait.
            const uint4* aS = inq + (size_t)n * CH + r;
            const uint4* a0 = inq + (size_t)cc[0] * CH + r;
            const uint4* a1 = inq + (size_t)cc[1] * CH + r;
            const uint4* a2 = inq + (size_t)cc[2] * CH + r;
            const uint4* a3 = inq + (size_t)cc[3] * CH + r;
            const uint4* a4 = inq + (size_t)cc[4] * CH + r;
            const uint4* a5 = inq + (size_t)cc[5] * CH + r;
            const uint4* a6 = inq + (size_t)cc[6] * CH + r;
            uint4 qs, q0, q1, q2, q3, q4, q5, q6;
            asm volatile(
                "global_load_dwordx4 %0, %8, off\n\t"
                "global_load_dwordx4 %1, %9, off\n\t"
                "global_load_dwordx4 %2, %10, off\n\t"
                "global_load_dwordx4 %3, %11, off\n\t"
                "global_load_dwordx4 %4, %12, off\n\t"
                "global_load_dwordx4 %5, %13, off\n\t"
                "global_load_dwordx4 %6, %14, off\n\t"
                "global_load_dwordx4 %7, %15, off\n\t"
                "s_waitcnt vmcnt(0)"
                : "=&v"(qs), "=&v"(q0), "=&v"(q1), "=&v"(q2),
                  "=&v"(q3), "=&v"(q4), "=&v"(q5), "=&v"(q6)
                : "v"(aS), "v"(a0), "v"(a1), "v"(a2),
                  "v"(a3), "v"(a4), "v"(a5), "v"(a6)
                : "memory");
            acc8(a, qs);
            if (dg > 0) acc8(a, q0);
            if (dg > 1) acc8(a, q1);
            if (dg > 2) acc8(a, q2);
            if (dg > 3) acc8(a, q3);
            if (dg > 4) acc8(a, q4);
            if (dg > 5) acc8(a, q5);
            if (dg > 6) acc8(a, q6);

            // burst 2: d7/d8 (buckets 7..8 only; wave-uniform branch).
            if (dg > 7) {
                const uint4* a7 = inq + (size_t)cc[7] * CH + r;
                const uint4* a8 = inq + (size_t)cc[8] * CH + r;
                uint4 q7, q8;
                asm volatile(
                    "global_load_dwordx4 %0, %2, off\n\t"
                    "global_load_dwordx4 %1, %3, off\n\t"
                    "s_waitcnt vmcnt(0)"
                    : "=&v"(q7), "=&v"(q8)
                    : "v"(a7), "v"(a8)
                    : "memory");
                acc8(a, q7);
                if (dg > 8) acc8(a, q8);
            }
        }

        if constexpr (AFF) {
            // tot = a_bn*(y_self + sum y_nb) + (deg+1)*c_bn, feats 8r..8r+7
            const float4* af = (const float4*)aff;
            float4 A0 = af[2 * r], A1 = af[2 * r + 1];
            float4 C0 = af[16 + 2 * r], C1 = af[16 + 2 * r + 1];
            float dp1 = (float)(dg + 1);
            a[0] = A0.x * a[0] + dp1 * C0.x;  a[1] = A0.y * a[1] + dp1 * C0.y;
            a[2] = A0.z * a[2] + dp1 * C0.z;  a[3] = A0.w * a[3] + dp1 * C0.w;
            a[4] = A1.x * a[4] + dp1 * C1.x;  a[5] = A1.y * a[5] + dp1 * C1.y;
            a[6] = A1.z * a[6] + dp1 * C1.z;  a[7] = A1.w * a[7] + dp1 * C1.w;
        }

        // transpose through LDS: sTot[wave][feat][node] (same-wave, no barrier)
#pragma unroll
        for (int j = 0; j < 8; ++j) sTot[wave][8 * r + j][t] = a[j];

        // matmul: lane = output o; 8 nodes per wave. unroll 4 = bounded liveness.
        float acc[8];
#pragma unroll
        for (int i = 0; i < 8; ++i) acc[i] = bterm;
#pragma unroll 4
        for (int j = 0; j < FI; ++j) {
            float w = sW[j * 63 + lane];   // lane 63 reads pad garbage; unused
            float4 u = *(const float4*)&sTot[wave][j][0];
            float4 v = *(const float4*)&sTot[wave][j][4];
            acc[0] = fmaf(u.x, w, acc[0]); acc[1] = fmaf(u.y, w, acc[1]);
            acc[2] = fmaf(u.z, w, acc[2]); acc[3] = fmaf(u.w, w, acc[3]);
            acc[4] = fmaf(v.x, w, acc[4]); acc[5] = fmaf(v.y, w, acc[5]);
            acc[6] = fmaf(v.z, w, acc[6]); acc[7] = fmaf(v.w, w, acc[7]);
        }

        // relu, store, accumulate per-lane stats
#pragma unroll
        for (int tt = 0; tt < 8; ++tt) {
            int nn = sN[wave][tt];
            float z = fmaxf(acc[tt], 0.f);
            if (nn >= 0 && lane < 63) {
                zout[(size_t)nn * ZST + lane] = f2b(z);
                lsum += z; lsq += z * z;
            }
        }
    }

    sRed[0][wave][lane] = lsum;
    sRed[1][wave][lane] = lsq;
    __syncthreads();
    if (wave == 0 && lane < 63) {
        float s = 0.f, q = 0.f;
#pragma unroll
        for (int w8 = 0; w8 < 8; ++w8) {
            s += sRed[0][w8][lane];
            q += sRed[1][w8][lane];
        }
        float* sp = spart + (size_t)(blockIdx.x & 255) * 128;
        atomicAdd(&sp[lane], s);
        atomicAdd(&sp[64 + lane], q);
    }
}

// ---------------- BN stats -> affine (a, c), parallel ----------------
// R17: one block per output channel, 256 threads load the 256 partials in
// parallel, LDS tree-reduce in double. ~2-3us (old serial form was ~9-10us).
__global__ void k_bn(const float* __restrict__ spart, const float* __restrict__ gamma,
                     const float* __restrict__ beta, float* __restrict__ afc) {
    __shared__ double sd[512];
    int o = blockIdx.x;            // 0..62
    int t = threadIdx.x;           // cp 0..255
    sd[t]       = (double)spart[t * 128 + o];
    sd[256 + t] = (double)spart[t * 128 + 64 + o];
    __syncthreads();
#pragma unroll
    for (int off = 128; off > 0; off >>= 1) {
        if (t < off) { sd[t] += sd[t + off]; sd[256 + t] += sd[256 + t + off]; }
        __syncthreads();
    }
    if (t == 0) {
        double mu  = sd[0] / NN;
        double var = sd[256] / NN - mu * mu;
        float a = (float)((double)gamma[o] / sqrt(var + 1e-5));
        float c = (float)((double)beta[o] - mu * (double)a);
        afc[o] = a;
        afc[64 + o] = c;
    }
}

// ---------------- prep for MFMA readout ----------------
// Emits:
//  bng2[128]: b_ng + sum_j c_j * W_ng[j][o]          (fp32, BN fold)
//  WngF: fragment-major bf16 hi/lo split of a_j*W_ng[j][o]:
//        [kblk 0..3][nt 0..7][lane 0..63][j 0..7], kblk 0,1 = hi(k 0..63),
//        kblk 2,3 = lo(k 0..63). k-slot = (lane>>4)*8 + j (self-consistent
//        with A-frag layout used in k_graph). Row k=63 zeroed (Z pad).
//  WtrF: fragment-major bf16 of W_tr: [nt 0..15][kblk 0..7][lane][j].
__global__ void k_prepw(const float* __restrict__ W_ng, const float* __restrict__ b_ng,
                        const float* __restrict__ afc2, const float* __restrict__ W_tr,
                        unsigned short* __restrict__ WngF, unsigned short* __restrict__ WtrF,
                        float* __restrict__ bng2) {
    int bid = blockIdx.x, tid = threadIdx.x;
    if (bid == 0) {
        if (tid < 128) {
            float acc = b_ng[tid];
            for (int j = 0; j < 63; ++j)
                acc = fmaf(afc2[64 + j], W_ng[j * 128 + tid], acc);
            bng2[tid] = acc;
        }
    } else if (bid <= 64) {
        int idx = (bid - 1) * 256 + tid;          // [0,16384)
        int j = idx & 7, lane = (idx >> 3) & 63;
        int nt = (idx >> 9) & 7, kb = idx >> 12;  // kb 0..3
        int k = (kb & 1) * 32 + ((lane >> 4) << 3) + j;
        int col = nt * 16 + (lane & 15);
        float w = (k < 63) ? afc2[k] * W_ng[k * 128 + col] : 0.f;
        unsigned short hi = f2b(w);
        if (kb < 2) WngF[idx] = hi;
        else        WngF[idx] = f2b(w - blo(hi));
    } else {
        int idx = (bid - 65) * 256 + tid;         // [0,65536)
        int j = idx & 7, lane = (idx >> 3) & 63;
        int kb = (idx >> 9) & 7, nt = idx >> 12;  // nt 0..15
        int k = kb * 32 + ((lane >> 4) << 3) + j;
        int col = nt * 16 + (lane & 15);
        WtrF[idx] = f2b(W_tr[k * 256 + col]);
    }
}

// ---------------- readout: MFMA over both GEMMs ----------------
// Block = 16 graphs = 320 nodes (grid 500). Wave owns 80 nodes = exactly 4
// graphs, so the C-fragment row (row=(lane>>4)*4+reg, col=lane&15 — verified
// layout) maps to graphs with one compile-time lane<16/32/48 select per
// boundary M-tile. Phase A: h = Z @ (W_hi + W_lo), K=128 MFMA (fp32-accurate
// weights; Z was already bf16). Segment sum/max folded in-register + butterfly
// shuffle; bias added after (monotone shift commutes with max). Phase B:
// out = tanh_T @ W_tr as 16x256x256 MFMA, B-frags streamed from L2-resident
// WtrF. sT is XOR-swizzled (idx ^ ((row&7)<<2)) so phase-B fragment reads
// (row stride 1 KB) are 2-way instead of 16-way bank-conflicted.
__global__ void __launch_bounds__(256, 2) k_graph(
    const unsigned short* __restrict__ Z2, const unsigned short* __restrict__ WngF,
    const float* __restrict__ bng2, const unsigned short* __restrict__ WtrF,
    const float* __restrict__ b_tr, float* __restrict__ out)
{
    __shared__ unsigned short sW[16384];     // 32 KB WngF frags
    __shared__ float sT[16 * 256];           // 16 KB tanh'd readout, swizzled
    __shared__ float sB[128];                // bng2

    int tid = threadIdx.x;
    int wave = tid >> 6, lane = tid & 63;
    int gl15 = lane & 15, grp = lane >> 4;

    // stage WngF (2048 uint4) + bng2
    {
        const uint4* srcq = (const uint4*)WngF;
        uint4* dstq = (uint4*)sW;
#pragma unroll
        for (int i = 0; i < 8; ++i) dstq[tid + 256 * i] = srcq[tid + 256 * i];
    }
    if (tid < 128) sB[tid] = bng2[tid];
    __syncthreads();

    // A-fragments: 5 M-tiles x (k0-31, k32-63). Lane l holds node (l&15),
    // k-slots (l>>4)*8.. — one contiguous uint4 of the Z row each.
    int nodeBase = blockIdx.x * 320 + wave * 80;
    const uint4* zq = (const uint4*)Z2;      // 8 uint4 per 64-bf16 row
    uint4 a0[5], a1[5];
#pragma unroll
    for (int m = 0; m < 5; ++m) {
        size_t row = (size_t)(nodeBase + m * 16 + gl15) * 8;
        a0[m] = zq[row + grp];
        a1[m] = zq[row + 4 + grp];
    }
    if (grp == 3) {                          // k=63 is pad (poison): zero it
#pragma unroll
        for (int m = 0; m < 5; ++m) a1[m].w &= 0xffffu;
    }

    const uint4* swq = (const uint4*)sW;
    const float NEGI = -3.0e38f;

#pragma unroll 1
    for (int nt = 0; nt < 8; ++nt) {
        U8 b0, b1, b2, b3;                   // kblk 0..3 (hi,hi,lo,lo)
        b0.u = swq[(0 * 8 + nt) * 64 + lane];
        b1.u = swq[(1 * 8 + nt) * 64 + lane];
        b2.u = swq[(2 * 8 + nt) * 64 + lane];
        b3.u = swq[(3 * 8 + nt) * 64 + lane];

        f32x4 ac[5];
#pragma unroll
        for (int m = 0; m < 5; ++m) {
            U8 xa0, xa1; xa0.u = a0[m]; xa1.u = a1[m];
            f32x4 c = {0.f, 0.f, 0.f, 0.f};
            c = __builtin_amdgcn_mfma_f32_16x16x32_bf16(xa0.b, b0.b, c, 0, 0, 0);
            c = __builtin_amdgcn_mfma_f32_16x16x32_bf16(xa1.b, b1.b, c, 0, 0, 0);
            c = __builtin_amdgcn_mfma_f32_16x16x32_bf16(xa0.b, b2.b, c, 0, 0, 0);
            c = __builtin_amdgcn_mfma_f32_16x16x32_bf16(xa1.b, b3.b, c, 0, 0, 0);
            ac[m] = c;
        }

        // fold rows into the wave's 4 graphs. wave-local row = m*16 + grp*4 + r.
        // m0 -> g0; m4 -> g3; m1 splits at lane16 (g0/g1); m2 at lane32
        // (g1/g2); m3 at lane48 (g2/g3).
        float s[4] = {0.f, 0.f, 0.f, 0.f};
        float x[4] = {NEGI, NEGI, NEGI, NEGI};
        bool cA = lane < 16, cB = lane < 32, cC = lane < 48;
#pragma unroll
        for (int r = 0; r < 4; ++r) {
            float v0 = ac[0][r]; s[0] += v0; x[0] = fmaxf(x[0], v0);
            float v4 = ac[4][r]; s[3] += v4; x[3] = fmaxf(x[3], v4);
            float v1 = ac[1][r]; float v1a = cA ? v1 : 0.f;
            s[0] += v1a; s[1] += v1 - v1a;
            x[0] = fmaxf(x[0], cA ? v1 : NEGI); x[1] = fmaxf(x[1], cA ? NEGI : v1);
            float v2 = ac[2][r]; float v2a = cB ? v2 : 0.f;
            s[1] += v2a; s[2] += v2 - v2a;
            x[1] = fmaxf(x[1], cB ? v2 : NEGI); x[2] = fmaxf(x[2], cB ? NEGI : v2);
            float v3 = ac[3][r]; float v3a = cC ? v3 : 0.f;
            s[2] += v3a; s[3] += v3 - v3a;
            x[2] = fmaxf(x[2], cC ? v3 : NEGI); x[3] = fmaxf(x[3], cC ? NEGI : v3);
        }
        // butterfly over the 4 lane groups (row partials live 16 lanes apart)
#pragma unroll
        for (int g = 0; g < 4; ++g) {
            s[g] += __shfl_xor(s[g], 16);
            s[g] += __shfl_xor(s[g], 32);
            x[g] = fmaxf(x[g], __shfl_xor(x[g], 16));
            x[g] = fmaxf(x[g], __shfl_xor(x[g], 32));
        }
        if (lane < 16) {
            int c = nt * 16 + lane;
            float bb = sB[c];
#pragma unroll
            for (int g = 0; g < 4; ++g) {
                int row = wave * 4 + g;
                int swz = (row & 7) << 2;
                sT[(row * 256 + c) ^ swz]       = tanhf(s[g] + 20.f * bb);
                sT[(row * 256 + 128 + c) ^ swz] = tanhf(x[g] + bb);
            }
        }
    }
    __syncthreads();

    // phase B: out[16 x 256] = T @ W_tr, K=256. A-frag: lane holds graph
    // g=lane&15, k-slots grp*8+.. read from swizzled sT and packed to bf16.
    U8 pa[8];
    {
        int swz = (gl15 & 7) << 2;
#pragma unroll
        for (int kb = 0; kb < 8; ++kb) {
            int k8 = kb * 32 + grp * 8;
            float4 t0 = *(const float4*)&sT[(gl15 * 256 + k8) ^ swz];
            float4 t1 = *(const float4*)&sT[(gl15 * 256 + k8 + 4) ^ swz];
            unsigned u0 = (unsigned)f2b(t0.x) | ((unsigned)f2b(t0.y) << 16);
            unsigned u1 = (unsigned)f2b(t0.z) | ((unsigned)f2b(t0.w) << 16);
            unsigned u2 = (unsigned)f2b(t1.x) | ((unsigned)f2b(t1.y) << 16);
            unsigned u3 = (unsigned)f2b(t1.z) | ((unsigned)f2b(t1.w) << 16);
            pa[kb].u = make_uint4(u0, u1, u2, u3);
        }
    }
    const uint4* wtq = (const uint4*)WtrF;
    size_t gbase = (size_t)blockIdx.x * 16 * 256;
#pragma unroll 2
    for (int i = 0; i < 4; ++i) {
        int nt = wave * 4 + i;
        f32x4 c = {0.f, 0.f, 0.f, 0.f};
#pragma unroll
        for (int kb = 0; kb < 8; ++kb) {
            U8 b; b.u = wtq[(nt * 8 + kb) * 64 + lane];
            c = __builtin_amdgcn_mfma_f32_16x16x32_bf16(pa[kb].b, b.b, c, 0, 0, 0);
        }
        int d = nt * 16 + gl15;
        float btv = b_tr[d];
#pragma unroll
        for (int r = 0; r < 4; ++r) {
            int row = grp * 4 + r;           // graph within block
            out[gbase + (size_t)row * 256 + d] = c[r] + btv;
        }
    }
}

// ---------------- launch ----------------
extern "C" void kernel_launch(void* const* d_in, const int* in_sizes, int n_in,
                              void* d_out, int out_size, void* d_ws, size_t ws_size,
                              hipStream_t stream) {
    const float* feats = (const float*)d_in[0];
    const int*   src   = (const int*)d_in[1];
    const int*   dst   = (const int*)d_in[2];
    // d_in[3] = graph_ids: repeat(arange(8000), 20) -> node/20, unused
    const float* W0 = (const float*)d_in[4];
    const float* b0 = (const float*)d_in[5];
    const float* g0 = (const float*)d_in[6];
    const float* be0 = (const float*)d_in[7];
    const float* W1 = (const float*)d_in[8];
    const float* b1 = (const float*)d_in[9];
    const float* g1 = (const float*)d_in[10];
    const float* be1 = (const float*)d_in[11];
    const float* W2 = (const float*)d_in[12];
    const float* b2 = (const float*)d_in[13];
    const float* g2 = (const float*)d_in[14];
    const float* be2 = (const float*)d_in[15];
    const float* Wng = (const float*)d_in[16];
    const float* bng = (const float*)d_in[17];
    const float* Wtr = (const float*)d_in[18];
    const float* btr = (const float*)d_in[19];
    float* out = (float*)d_out;

    char* ws = (char*)d_ws;
    int*    degcnt  = (int*)(ws + OFF_DEGCNT);
    int*    cursor  = (int*)(ws + OFF_CURSOR);
    int*    bcnt    = (int*)(ws + OFF_BCNT);
    int*    ctr     = bcnt + 10;                    // counters (zeroed)
    float*  spart   = (float*)(ws + OFF_SPART);
    int*    row_ptr = (int*)(ws + OFF_ROWPTR);
    int*    blksum  = (int*)(ws + OFF_BLKSUM);
    int*    col     = (int*)(ws + OFF_COL);
    int2*   blist   = (int2*)(ws + OFF_BLIST);
    float*  afc     = (float*)(ws + OFF_AFC);
    float*  bng2    = (float*)(ws + OFF_BNG2);
    int*    pblk    = (int*)(ws + OFF_PBLK);
    unsigned short* Fb = (unsigned short*)(ws + OFF_FB);
    unsigned short* Z0 = (unsigned short*)(ws + OFF_Z0);
    unsigned short* Z1 = (unsigned short*)(ws + OFF_Z1);
    unsigned short* Z2 = Z0;   // layer2 output reuses Z0
    unsigned short* WngF = (unsigned short*)(ws + OFF_WNGF);  // in Z1 (free)
    unsigned short* WtrF = (unsigned short*)(ws + OFF_WTRF);  // in Z1 (free)

    hipMemsetAsync(d_ws, 0, ZERO_BYTES, stream);

    k_cast<<<NN * FST / 256, 256, 0, stream>>>(feats, Fb, dst, degcnt);
    k_scan1<<<157, 1024, 0, stream>>>(degcnt, row_ptr, blksum);
    k_scan2<<<1, 256, 0, stream>>>(blksum, 157);
    k_scan3<<<157, 1024, 0, stream>>>(row_ptr, blksum);
    k_bucket<<<157, 1024, 0, stream>>>(degcnt, row_ptr, bcnt, blist, pblk, ctr);
    k_fill<<<NE / 256, 256, 0, stream>>>(src, dst, row_ptr, cursor, col);

    k_layer<74, FST, false><<<LGRID, 512, 0, stream>>>(
        Fb, nullptr, row_ptr, col, bcnt, blist, pblk, W0, b0, Z0, spart);
    k_bn<<<63, 256, 0, stream>>>(spart, g0, be0, afc);
    k_layer<63, ZST, true><<<LGRID, 512, 0, stream>>>(
        Z0, afc, row_ptr, col, bcnt, blist, pblk, W1, b1, Z1, spart + 256 * 128);
    k_bn<<<63, 256, 0, stream>>>(spart + 256 * 128, g1, be1, afc + 128);
    k_layer<63, ZST, true><<<LGRID, 512, 0, stream>>>(
        Z1, afc + 128, row_ptr, col, bcnt, blist, pblk, W2, b2, Z2, spart + 2 * 256 * 128);
    k_bn<<<63, 256, 0, stream>>>(spart + 2 * 256 * 128, g2, be2, afc + 256);

    // prep fragments (Z1 region is dead after layer2 consumed it)
    k_prepw<<<321, 256, 0, stream>>>(Wng, bng, afc + 256, Wtr, WngF, WtrF, bng2);
    k_graph<<<NG / 16, 256, 0, stream>>>(Z2, WngF, bng2, WtrF, btr, out);
}

// Round 13
// 428.246 us; speedup vs baseline: 1.0020x; 1.0020x over previous
//
#include <hip/hip_runtime.h>
#include <stdint.h>
#include <math.h>

// ---------------- problem constants ----------------
static constexpr int NN = 160000;   // nodes
static constexpr int NE = 640000;   // edges
static constexpr int NG = 8000;     // graphs (20 nodes each, contiguous)
static constexpr int FH  = 63;      // hidden
static constexpr int ZST = 64;      // bf16 elems per Z row (128 B)
static constexpr int FST = 80;      // bf16 elems per feats row (160 B)
static constexpr int NB  = 128;     // nodes per block (8 waves x 8 x 2 iters)
static constexpr int LGRID = 1536;  // >= sum_k ceil(cnt_k/NB) <= ~1260

// ---------------- workspace layout (bytes) ----------------
static constexpr size_t OFF_DEGCNT = 0;                       // 160000 i32
static constexpr size_t OFF_CURSOR = 640000;                  // 160000 i32
static constexpr size_t OFF_BCNT   = 1280000;                 // 16 i32 (10 bcnt + ctrs)
static constexpr size_t OFF_SPART  = 1280064;                 // 3*256*128 f32 -> 1673280
static constexpr size_t OFF_NBR    = 1673280;                 // 160000*12 i32 (padded nbr table, zeroed)
static constexpr size_t ZERO_BYTES = 9353280;                 // everything above zeroed
static constexpr size_t OFF_ROWPTR = 9353280;                 // 160001 i32
static constexpr size_t OFF_BLKSUM = 9994048;                 // 512 i32
static constexpr size_t OFF_COL    = 9996096;                 // 640000 i32
static constexpr size_t OFF_NSLOT  = 12556096;                // 160000 i32 (k<<24 | slot)
static constexpr size_t OFF_BLIST  = 13196096;                // 10*160000 i32 (node id)
static constexpr size_t OFF_AFC    = 19596096;                // 3*2*64 f32
static constexpr size_t OFF_BNG2   = 19596864;                // 128 f32
static constexpr size_t OFF_PBLK   = 19597376;                // 11 pblk + 10 ebase i32
static constexpr size_t OFF_FB     = 19597504;                // 160000*80 bf16 (feats cast), 16B-aligned
static constexpr size_t OFF_Z0     = 45197504;                // 160000*64 bf16
static constexpr size_t OFF_Z1     = 65677504;                // 160000*64 bf16 (free after layer2)
// Z1 region reused after layer2 for the readout weight fragments:
static constexpr size_t OFF_WNGF   = OFF_Z1;                  // 32 KB
static constexpr size_t OFF_WTRF   = OFF_Z1 + 32768;          // 128 KB
// total ~86.2 MB

// ---------------- bf16 helpers ----------------
__device__ __forceinline__ float blo(unsigned u) {
    union { unsigned i; float f; } v; v.i = u << 16; return v.f;
}
__device__ __forceinline__ float bhi(unsigned u) {
    union { unsigned i; float f; } v; v.i = u & 0xffff0000u; return v.f;
}
__device__ __forceinline__ unsigned short f2b(float f) {
    union { float f; unsigned i; } v; v.f = f;
    unsigned r = v.i + 0x7fffu + ((v.i >> 16) & 1u);
    return (unsigned short)(r >> 16);
}
// accumulate 8 bf16 (one uint4) into 8 f32
__device__ __forceinline__ void acc8(float* a, uint4 q) {
    a[0] += blo(q.x); a[1] += bhi(q.x);
    a[2] += blo(q.y); a[3] += bhi(q.y);
    a[4] += blo(q.z); a[5] += bhi(q.z);
    a[6] += blo(q.w); a[7] += bhi(q.w);
}

// ---------------- MFMA types ----------------
typedef __attribute__((ext_vector_type(8))) short bf16x8;
typedef __attribute__((ext_vector_type(4))) float f32x4;
union U8 { uint4 u; bf16x8 b; };

// ---------------- fused cast + degree ----------------
__global__ void k_cast(const float* __restrict__ feats, unsigned short* __restrict__ fb,
                       const int* __restrict__ dst, int* __restrict__ degcnt) {
    int i = blockIdx.x * 256 + threadIdx.x;
    if (i < NE) atomicAdd(&degcnt[dst[i]], 1);
    if (i >= NN * FST) return;
    int n = i / FST, c = i - n * FST;
    float v = (c < 74) ? feats[n * 74 + c] : 0.f;
    union { float f; unsigned u; } x; x.f = v;
    unsigned r = x.u + 0x7fffu + ((x.u >> 16) & 1u);
    fb[i] = (unsigned short)(r >> 16);
}

__global__ void k_scan1(const int* __restrict__ degcnt, int* __restrict__ row_ptr,
                        int* __restrict__ blksum) {
    __shared__ int s[1024];
    int t = threadIdx.x;
    int i = blockIdx.x * 1024 + t;
    int v = (i < NN) ? degcnt[i] : 0;
    s[t] = v; __syncthreads();
    for (int off = 1; off < 1024; off <<= 1) {
        int x = (t >= off) ? s[t - off] : 0;
        __syncthreads();
        s[t] += x;
        __syncthreads();
    }
    if (i < NN) row_ptr[i + 1] = s[t];
    if (t == 1023) blksum[blockIdx.x] = s[t];
}

__global__ void k_scan2(int* __restrict__ blksum, int nblk) {
    __shared__ int s[256];
    int t = threadIdx.x;
    int v = (t < nblk) ? blksum[t] : 0;
    s[t] = v; __syncthreads();
    for (int off = 1; off < 256; off <<= 1) {
        int x = (t >= off) ? s[t - off] : 0;
        __syncthreads();
        s[t] += x;
        __syncthreads();
    }
    if (t < nblk) blksum[t] = s[t] - v;
}

__global__ void k_scan3(int* __restrict__ row_ptr, const int* __restrict__ blksum) {
    int t = threadIdx.x;
    int i = blockIdx.x * 1024 + t;
    if (i < NN) row_ptr[i + 1] += blksum[blockIdx.x];
    if (i == 0) row_ptr[0] = 0;
}

// LDS-aggregated bucket build; stores node id + per-node slot (k<<24|slot).
// Last-finishing block computes pblk AND ebase (bucket-start prefix for the
// dense padded neighbor table). Cold kernel: fence is cheap here.
__global__ void __launch_bounds__(1024) k_bucket(
        const int* __restrict__ degcnt, const int* __restrict__ row_ptr,
        int* __restrict__ bcnt, int* __restrict__ blist,
        int* __restrict__ nodeslot,
        int* __restrict__ pblk, int* __restrict__ ctr) {
    __shared__ int scnt[10], sbase[10];
    __shared__ int sLast;
    int tid = threadIdx.x;
    if (tid < 10) scnt[tid] = 0;
    __syncthreads();
    int n = blockIdx.x * 1024 + tid;
    int k = 0, pos = 0;
    bool v = (n < NN);
    if (v) {
        int d = degcnt[n];
        k = (d < 1) ? 0 : ((d > 10) ? 9 : d - 1);
        pos = atomicAdd(&scnt[k], 1);
    }
    __syncthreads();
    if (tid < 10) sbase[tid] = scnt[tid] ? atomicAdd(&bcnt[tid], scnt[tid]) : 0;
    __syncthreads();
    if (v) {
        int slot = sbase[k] + pos;
        blist[k * NN + slot] = n;
        nodeslot[n] = (k << 24) | slot;
    }

    // last-block-done: compute pblk + ebase
    if (tid == 0) {
        __threadfence();
        sLast = (atomicAdd(ctr, 1) == (int)gridDim.x - 1) ? 1 : 0;
    }
    __syncthreads();
    if (sLast && tid == 0) {
        __threadfence();
        const volatile int* bc = bcnt;
        int s = 0; pblk[0] = 0;
        int eacc = 0;
        for (int kk = 0; kk < 10; ++kk) {
            s += (bc[kk] + NB - 1) / NB; pblk[kk + 1] = s;
            pblk[11 + kk] = eacc; eacc += bc[kk];
        }
    }
}

// fill CSR col (bucket-9 path) AND the dense padded neighbor table
// nbr[(ebase[k]+slot)*12 + cur] for deg<=9 nodes. Same cursor ordering as
// col => identical accumulation order => bit-identical FP.
__global__ void k_fill(const int* __restrict__ src, const int* __restrict__ dst,
                       const int* __restrict__ row_ptr, int* __restrict__ cursor,
                       int* __restrict__ col, const int* __restrict__ nodeslot,
                       const int* __restrict__ ebase, int* __restrict__ nbr) {
    int e = blockIdx.x * 256 + threadIdx.x;
    if (e >= NE) return;
    int d = dst[e];
    int sv = src[e];
    int cur = atomicAdd(&cursor[d], 1);
    col[row_ptr[d] + cur] = sv;
    int s = nodeslot[d];
    int kk = s >> 24;
    if (kk < 9) {
        int row = ebase[kk] + (s & 0xFFFFFF);
        nbr[row * 12 + cur] = sv;
    }
}

// ---------------- NF layer: affine-index gather, 128 nodes/block, 8 waves ----------------
// R19-R21 lesson: the compiler cannot be out-scheduled inside the wave (cond
// ladder spilled; clamped burst re-serialized; asm vmcnt(0) over-synced).
// R22 (this): remove a DEPENDENCY LEVEL structurally. Old chain per node:
// blist->rs->col->gather (3 levels). Now neighbor indices live in a dense
// padded table addressed by (ebase[k] + idx) — affine, no prior load — so
// the chains are blist->self-gather and nbr->nbr-gathers, both 2-level, and
// the index fetch is a coalesced 3x int4 stream. Zero-padded slots load node
// 0's L1-hot line; accumulation masked by d<dg in self->ascending order:
// bit-identical FP. Bucket 9 (deg>=10, 0.8%) keeps the dynamic col path.
// Tripwires: VGPR<=64, WRITE ~21MB (no spill).
template<int FI, int IST, bool AFF>
__global__ void __launch_bounds__(512, 4) k_layer(
    const unsigned short* __restrict__ in,
    const float* __restrict__ aff,
    const int* __restrict__ row_ptr, const int* __restrict__ col,
    const int* __restrict__ bcnt, const int* __restrict__ blist,
    const int* __restrict__ pblk, const int* __restrict__ nbr,
    const float* __restrict__ W, const float* __restrict__ B,
    unsigned short* __restrict__ zout, float* __restrict__ spart)
{
    constexpr int CH = IST / 8;      // uint4 chunks per row (64->8, 80->10)
    __shared__ float sW[FI * 63 + 64];
    __shared__ float sTot[8][IST][8];
    __shared__ int   sN[8][8];
    __shared__ float sRed[2][8][64];

    int b = blockIdx.x;
    if (b >= pblk[10]) return;
    int k = 0;
#pragma unroll
    for (int i = 1; i <= 9; ++i) k += (b >= pblk[i]) ? 1 : 0;   // uniform (sgpr)
    int base = (b - pblk[k]) * NB;
    int cnt = bcnt[k];
    if (base >= cnt) return;
    int ebs = pblk[11 + k];          // bucket start in nbr table (uniform)

    int tid = threadIdx.x;
    int wave = tid >> 6, lane = tid & 63;
    int t = lane >> 3, r = lane & 7;

    const float* Wk = W + (size_t)k * FI * 63;
#pragma unroll 4
    for (int i = tid; i < FI * 63; i += 512) sW[i] = Wk[i];
    __syncthreads();

    const uint4* inq = (const uint4*)in;
    float bterm = (lane < 63) ? B[k * 63 + lane] : 0.f;
    float lsum = 0.f, lsq = 0.f;

#pragma unroll 1
    for (int it = 0; it < NB / 64; ++it) {
        int idx = base + it * 64 + wave * 8 + t;
        if (base + it * 64 >= cnt) break;                 // whole-batch empty (uniform)
        bool val = (idx < cnt);
        int idxc = val ? idx : (cnt - 1);
        int n = blist[k * NN + idxc];
        // buckets 1..8: deg == k+1 exactly (uniform). 0 and 9: per-node.
        int dg;
        if (k >= 1 && k <= 8) dg = k + 1;
        else dg = row_ptr[n + 1] - row_ptr[n];
        if (r == 0) sN[wave][t] = val ? n : -1;

        float a[8] = {0.f, 0.f, 0.f, 0.f, 0.f, 0.f, 0.f, 0.f};

        if (k == 9) {
            // ---------- dynamic path (deg >= 10, ~0.8% of nodes) ----------
            int rs = row_ptr[n];
            {
                uint4 q = inq[(size_t)n * CH + r];
                acc8(a, q);
            }
            int d = 0;
#pragma unroll 1
            for (; d + 4 <= dg; d += 4) {
                int c0 = col[rs + d], c1 = col[rs + d + 1];
                int c2 = col[rs + d + 2], c3 = col[rs + d + 3];
                uint4 q0 = inq[(size_t)c0 * CH + r];
                uint4 q1 = inq[(size_t)c1 * CH + r];
                uint4 q2 = inq[(size_t)c2 * CH + r];
                uint4 q3 = inq[(size_t)c3 * CH + r];
                acc8(a, q0); acc8(a, q1); acc8(a, q2); acc8(a, q3);
            }
#pragma unroll 1
            for (; d < dg; ++d) {
                int c = col[rs + d];
                uint4 q = inq[(size_t)c * CH + r];
                acc8(a, q);
            }
            if constexpr (IST == 80) {
                float e2[8] = {0.f, 0.f, 0.f, 0.f, 0.f, 0.f, 0.f, 0.f};
                if (r < 2) {
                    uint4 q = inq[(size_t)n * CH + 8 + r];
                    acc8(e2, q);
                    int d2 = 0;
#pragma unroll 1
                    for (; d2 < dg; ++d2) {
                        int c = col[rs + d2];
                        uint4 p = inq[(size_t)c * CH + 8 + r];
                        acc8(e2, p);
                    }
#pragma unroll
                    for (int j = 0; j < 8; ++j) sTot[wave][64 + 8 * r + j][t] = e2[j];
                }
            }
        } else {
            // ---------- affine-index gather (deg <= 9) ----------
            const int4* nb4 = (const int4*)(nbr + (size_t)(ebs + idxc) * 12);
            int4 w0 = nb4[0], w1 = nb4[1], w2 = nb4[2];
            int c0 = w0.x, c1 = w0.y, c2 = w0.z, c3 = w0.w;
            int c4 = w1.x, c5 = w1.y, c6 = w1.z, c7 = w1.w;
            int c8 = w2.x;

            // L0 extra chunks first (r<2): disjoint transient register set.
            if constexpr (IST == 80) {
                if (r < 2) {
                    float e2[8] = {0.f, 0.f, 0.f, 0.f, 0.f, 0.f, 0.f, 0.f};
                    uint4 ps = inq[(size_t)n * CH + 8 + r];
                    uint4 p0 = inq[(size_t)c0 * CH + 8 + r];
                    uint4 p1 = inq[(size_t)c1 * CH + 8 + r];
                    uint4 p2 = inq[(size_t)c2 * CH + 8 + r];
                    uint4 p3 = inq[(size_t)c3 * CH + 8 + r];
                    uint4 p4 = inq[(size_t)c4 * CH + 8 + r];
                    uint4 p5 = inq[(size_t)c5 * CH + 8 + r];
                    uint4 p6 = inq[(size_t)c6 * CH + 8 + r];
                    uint4 p7 = inq[(size_t)c7 * CH + 8 + r];
                    uint4 p8 = inq[(size_t)c8 * CH + 8 + r];
                    acc8(e2, ps);
                    if (dg > 0) acc8(e2, p0);
                    if (dg > 1) acc8(e2, p1);
                    if (dg > 2) acc8(e2, p2);
                    if (dg > 3) acc8(e2, p3);
                    if (dg > 4) acc8(e2, p4);
                    if (dg > 5) acc8(e2, p5);
                    if (dg > 6) acc8(e2, p6);
                    if (dg > 7) acc8(e2, p7);
                    if (dg > 8) acc8(e2, p8);
#pragma unroll
                    for (int j = 0; j < 8; ++j) sTot[wave][64 + 8 * r + j][t] = e2[j];
                }
            }

            uint4 qs = inq[(size_t)n * CH + r];
            uint4 q0 = inq[(size_t)c0 * CH + r];
            uint4 q1 = inq[(size_t)c1 * CH + r];
            uint4 q2 = inq[(size_t)c2 * CH + r];
            uint4 q3 = inq[(size_t)c3 * CH + r];
            uint4 q4 = inq[(size_t)c4 * CH + r];
            uint4 q5 = inq[(size_t)c5 * CH + r];
            uint4 q6 = inq[(size_t)c6 * CH + r];
            uint4 q7 = inq[(size_t)c7 * CH + r];
            uint4 q8 = inq[(size_t)c8 * CH + r];
            acc8(a, qs);
            if (dg > 0) acc8(a, q0);
            if (dg > 1) acc8(a, q1);
            if (dg > 2) acc8(a, q2);
            if (dg > 3) acc8(a, q3);
            if (dg > 4) acc8(a, q4);
            if (dg > 5) acc8(a, q5);
            if (dg > 6) acc8(a, q6);
            if (dg > 7) acc8(a, q7);
            if (dg > 8) acc8(a, q8);
        }

        if constexpr (AFF) {
            // tot = a_bn*(y_self + sum y_nb) + (deg+1)*c_bn, feats 8r..8r+7
            const float4* af = (const float4*)aff;
            float4 A0 = af[2 * r], A1 = af[2 * r + 1];
            float4 C0 = af[16 + 2 * r], C1 = af[16 + 2 * r + 1];
            float dp1 = (float)(dg + 1);
            a[0] = A0.x * a[0] + dp1 * C0.x;  a[1] = A0.y * a[1] + dp1 * C0.y;
            a[2] = A0.z * a[2] + dp1 * C0.z;  a[3] = A0.w * a[3] + dp1 * C0.w;
            a[4] = A1.x * a[4] + dp1 * C1.x;  a[5] = A1.y * a[5] + dp1 * C1.y;
            a[6] = A1.z * a[6] + dp1 * C1.z;  a[7] = A1.w * a[7] + dp1 * C1.w;
        }

        // transpose through LDS: sTot[wave][feat][node] (same-wave, no barrier)
#pragma unroll
        for (int j = 0; j < 8; ++j) sTot[wave][8 * r + j][t] = a[j];

        // matmul: lane = output o; 8 nodes per wave. unroll 4 = bounded liveness.
        float acc[8];
#pragma unroll
        for (int i = 0; i < 8; ++i) acc[i] = bterm;
#pragma unroll 4
        for (int j = 0; j < FI; ++j) {
            float w = sW[j * 63 + lane];   // lane 63 reads pad garbage; unused
            float4 u = *(const float4*)&sTot[wave][j][0];
            float4 v = *(const float4*)&sTot[wave][j][4];
            acc[0] = fmaf(u.x, w, acc[0]); acc[1] = fmaf(u.y, w, acc[1]);
            acc[2] = fmaf(u.z, w, acc[2]); acc[3] = fmaf(u.w, w, acc[3]);
            acc[4] = fmaf(v.x, w, acc[4]); acc[5] = fmaf(v.y, w, acc[5]);
            acc[6] = fmaf(v.z, w, acc[6]); acc[7] = fmaf(v.w, w, acc[7]);
        }

        // relu, store, accumulate per-lane stats
#pragma unroll
        for (int tt = 0; tt < 8; ++tt) {
            int nn = sN[wave][tt];
            float z = fmaxf(acc[tt], 0.f);
            if (nn >= 0 && lane < 63) {
                zout[(size_t)nn * ZST + lane] = f2b(z);
                lsum += z; lsq += z * z;
            }
        }
    }

    sRed[0][wave][lane] = lsum;
    sRed[1][wave][lane] = lsq;
    __syncthreads();
    if (wave == 0 && lane < 63) {
        float s = 0.f, q = 0.f;
#pragma unroll
        for (int w8 = 0; w8 < 8; ++w8) {
            s += sRed[0][w8][lane];
            q += sRed[1][w8][lane];
        }
        float* sp = spart + (size_t)(blockIdx.x & 255) * 128;
        atomicAdd(&sp[lane], s);
        atomicAdd(&sp[64 + lane], q);
    }
}

// ---------------- BN stats -> affine (a, c), parallel ----------------
__global__ void k_bn(const float* __restrict__ spart, const float* __restrict__ gamma,
                     const float* __restrict__ beta, float* __restrict__ afc) {
    __shared__ double sd[512];
    int o = blockIdx.x;            // 0..62
    int t = threadIdx.x;           // cp 0..255
    sd[t]       = (double)spart[t * 128 + o];
    sd[256 + t] = (double)spart[t * 128 + 64 + o];
    __syncthreads();
#pragma unroll
    for (int off = 128; off > 0; off >>= 1) {
        if (t < off) { sd[t] += sd[t + off]; sd[256 + t] += sd[256 + t + off]; }
        __syncthreads();
    }
    if (t == 0) {
        double mu  = sd[0] / NN;
        double var = sd[256] / NN - mu * mu;
        float a = (float)((double)gamma[o] / sqrt(var + 1e-5));
        float c = (float)((double)beta[o] - mu * (double)a);
        afc[o] = a;
        afc[64 + o] = c;
    }
}

// ---------------- prep for MFMA readout ----------------
__global__ void k_prepw(const float* __restrict__ W_ng, const float* __restrict__ b_ng,
                        const float* __restrict__ afc2, const float* __restrict__ W_tr,
                        unsigned short* __restrict__ WngF, unsigned short* __restrict__ WtrF,
                        float* __restrict__ bng2) {
    int bid = blockIdx.x, tid = threadIdx.x;
    if (bid == 0) {
        if (tid < 128) {
            float acc = b_ng[tid];
            for (int j = 0; j < 63; ++j)
                acc = fmaf(afc2[64 + j], W_ng[j * 128 + tid], acc);
            bng2[tid] = acc;
        }
    } else if (bid <= 64) {
        int idx = (bid - 1) * 256 + tid;          // [0,16384)
        int j = idx & 7, lane = (idx >> 3) & 63;
        int nt = (idx >> 9) & 7, kb = idx >> 12;  // kb 0..3
        int k = (kb & 1) * 32 + ((lane >> 4) << 3) + j;
        int col = nt * 16 + (lane & 15);
        float w = (k < 63) ? afc2[k] * W_ng[k * 128 + col] : 0.f;
        unsigned short hi = f2b(w);
        if (kb < 2) WngF[idx] = hi;
        else        WngF[idx] = f2b(w - blo(hi));
    } else {
        int idx = (bid - 65) * 256 + tid;         // [0,65536)
        int j = idx & 7, lane = (idx >> 3) & 63;
        int kb = (idx >> 9) & 7, nt = idx >> 12;  // nt 0..15
        int k = kb * 32 + ((lane >> 4) << 3) + j;
        int col = nt * 16 + (lane & 15);
        WtrF[idx] = f2b(W_tr[k * 256 + col]);
    }
}

// ---------------- readout: MFMA over both GEMMs ----------------
__global__ void __launch_bounds__(256, 2) k_graph(
    const unsigned short* __restrict__ Z2, const unsigned short* __restrict__ WngF,
    const float* __restrict__ bng2, const unsigned short* __restrict__ WtrF,
    const float* __restrict__ b_tr, float* __restrict__ out)
{
    __shared__ unsigned short sW[16384];     // 32 KB WngF frags
    __shared__ float sT[16 * 256];           // 16 KB tanh'd readout, swizzled
    __shared__ float sB[128];                // bng2

    int tid = threadIdx.x;
    int wave = tid >> 6, lane = tid & 63;
    int gl15 = lane & 15, grp = lane >> 4;

    // stage WngF (2048 uint4) + bng2
    {
        const uint4* srcq = (const uint4*)WngF;
        uint4* dstq = (uint4*)sW;
#pragma unroll
        for (int i = 0; i < 8; ++i) dstq[tid + 256 * i] = srcq[tid + 256 * i];
    }
    if (tid < 128) sB[tid] = bng2[tid];
    __syncthreads();

    // A-fragments: 5 M-tiles x (k0-31, k32-63). Lane l holds node (l&15),
    // k-slots (l>>4)*8.. — one contiguous uint4 of the Z row each.
    int nodeBase = blockIdx.x * 320 + wave * 80;
    const uint4* zq = (const uint4*)Z2;      // 8 uint4 per 64-bf16 row
    uint4 a0[5], a1[5];
#pragma unroll
    for (int m = 0; m < 5; ++m) {
        size_t row = (size_t)(nodeBase + m * 16 + gl15) * 8;
        a0[m] = zq[row + grp];
        a1[m] = zq[row + 4 + grp];
    }
    if (grp == 3) {                          // k=63 is pad (poison): zero it
#pragma unroll
        for (int m = 0; m < 5; ++m) a1[m].w &= 0xffffu;
    }

    const uint4* swq = (const uint4*)sW;
    const float NEGI = -3.0e38f;

#pragma unroll 1
    for (int nt = 0; nt < 8; ++nt) {
        U8 b0, b1, b2, b3;                   // kblk 0..3 (hi,hi,lo,lo)
        b0.u = swq[(0 * 8 + nt) * 64 + lane];
        b1.u = swq[(1 * 8 + nt) * 64 + lane];
        b2.u = swq[(2 * 8 + nt) * 64 + lane];
        b3.u = swq[(3 * 8 + nt) * 64 + lane];

        f32x4 ac[5];
#pragma unroll
        for (int m = 0; m < 5; ++m) {
            U8 xa0, xa1; xa0.u = a0[m]; xa1.u = a1[m];
            f32x4 c = {0.f, 0.f, 0.f, 0.f};
            c = __builtin_amdgcn_mfma_f32_16x16x32_bf16(xa0.b, b0.b, c, 0, 0, 0);
            c = __builtin_amdgcn_mfma_f32_16x16x32_bf16(xa1.b, b1.b, c, 0, 0, 0);
            c = __builtin_amdgcn_mfma_f32_16x16x32_bf16(xa0.b, b2.b, c, 0, 0, 0);
            c = __builtin_amdgcn_mfma_f32_16x16x32_bf16(xa1.b, b3.b, c, 0, 0, 0);
            ac[m] = c;
        }

        // fold rows into the wave's 4 graphs. wave-local row = m*16 + grp*4 + r.
        float s[4] = {0.f, 0.f, 0.f, 0.f};
        float x[4] = {NEGI, NEGI, NEGI, NEGI};
        bool cA = lane < 16, cB = lane < 32, cC = lane < 48;
#pragma unroll
        for (int r = 0; r < 4; ++r) {
            float v0 = ac[0][r]; s[0] += v0; x[0] = fmaxf(x[0], v0);
            float v4 = ac[4][r]; s[3] += v4; x[3] = fmaxf(x[3], v4);
            float v1 = ac[1][r]; float v1a = cA ? v1 : 0.f;
            s[0] += v1a; s[1] += v1 - v1a;
            x[0] = fmaxf(x[0], cA ? v1 : NEGI); x[1] = fmaxf(x[1], cA ? NEGI : v1);
            float v2 = ac[2][r]; float v2a = cB ? v2 : 0.f;
            s[1] += v2a; s[2] += v2 - v2a;
            x[1] = fmaxf(x[1], cB ? v2 : NEGI); x[2] = fmaxf(x[2], cB ? NEGI : v2);
            float v3 = ac[3][r]; float v3a = cC ? v3 : 0.f;
            s[2] += v3a; s[3] += v3 - v3a;
            x[2] = fmaxf(x[2], cC ? v3 : NEGI); x[3] = fmaxf(x[3], cC ? NEGI : v3);
        }
        // butterfly over the 4 lane groups (row partials live 16 lanes apart)
#pragma unroll
        for (int g = 0; g < 4; ++g) {
            s[g] += __shfl_xor(s[g], 16);
            s[g] += __shfl_xor(s[g], 32);
            x[g] = fmaxf(x[g], __shfl_xor(x[g], 16));
            x[g] = fmaxf(x[g], __shfl_xor(x[g], 32));
        }
        if (lane < 16) {
            int c = nt * 16 + lane;
            float bb = sB[c];
#pragma unroll
            for (int g = 0; g < 4; ++g) {
                int row = wave * 4 + g;
                int swz = (row & 7) << 2;
                sT[(row * 256 + c) ^ swz]       = tanhf(s[g] + 20.f * bb);
                sT[(row * 256 + 128 + c) ^ swz] = tanhf(x[g] + bb);
            }
        }
    }
    __syncthreads();

    // phase B: out[16 x 256] = T @ W_tr, K=256.
    U8 pa[8];
    {
        int swz = (gl15 & 7) << 2;
#pragma unroll
        for (int kb = 0; kb < 8; ++kb) {
            int k8 = kb * 32 + grp * 8;
            float4 t0 = *(const float4*)&sT[(gl15 * 256 + k8) ^ swz];
            float4 t1 = *(const float4*)&sT[(gl15 * 256 + k8 + 4) ^ swz];
            unsigned u0 = (unsigned)f2b(t0.x) | ((unsigned)f2b(t0.y) << 16);
            unsigned u1 = (unsigned)f2b(t0.z) | ((unsigned)f2b(t0.w) << 16);
            unsigned u2 = (unsigned)f2b(t1.x) | ((unsigned)f2b(t1.y) << 16);
            unsigned u3 = (unsigned)f2b(t1.z) | ((unsigned)f2b(t1.w) << 16);
            pa[kb].u = make_uint4(u0, u1, u2, u3);
        }
    }
    const uint4* wtq = (const uint4*)WtrF;
    size_t gbase = (size_t)blockIdx.x * 16 * 256;
#pragma unroll 2
    for (int i = 0; i < 4; ++i) {
        int nt = wave * 4 + i;
        f32x4 c = {0.f, 0.f, 0.f, 0.f};
#pragma unroll
        for (int kb = 0; kb < 8; ++kb) {
            U8 b; b.u = wtq[(nt * 8 + kb) * 64 + lane];
            c = __builtin_amdgcn_mfma_f32_16x16x32_bf16(pa[kb].b, b.b, c, 0, 0, 0);
        }
        int d = nt * 16 + gl15;
        float btv = b_tr[d];
#pragma unroll
        for (int r = 0; r < 4; ++r) {
            int row = grp * 4 + r;           // graph within block
            out[gbase + (size_t)row * 256 + d] = c[r] + btv;
        }
    }
}

// ---------------- launch ----------------
extern "C" void kernel_launch(void* const* d_in, const int* in_sizes, int n_in,
                              void* d_out, int out_size, void* d_ws, size_t ws_size,
                              hipStream_t stream) {
    const float* feats = (const float*)d_in[0];
    const int*   src   = (const int*)d_in[1];
    const int*   dst   = (const int*)d_in[2];
    // d_in[3] = graph_ids: repeat(arange(8000), 20) -> node/20, unused
    const float* W0 = (const float*)d_in[4];
    const float* b0 = (const float*)d_in[5];
    const float* g0 = (const float*)d_in[6];
    const float* be0 = (const float*)d_in[7];
    const float* W1 = (const float*)d_in[8];
    const float* b1 = (const float*)d_in[9];
    const float* g1 = (const float*)d_in[10];
    const float* be1 = (const float*)d_in[11];
    const float* W2 = (const float*)d_in[12];
    const float* b2 = (const float*)d_in[13];
    const float* g2 = (const float*)d_in[14];
    const float* be2 = (const float*)d_in[15];
    const float* Wng = (const float*)d_in[16];
    const float* bng = (const float*)d_in[17];
    const float* Wtr = (const float*)d_in[18];
    const float* btr = (const float*)d_in[19];
    float* out = (float*)d_out;

    char* ws = (char*)d_ws;
    int*    degcnt  = (int*)(ws + OFF_DEGCNT);
    int*    cursor  = (int*)(ws + OFF_CURSOR);
    int*    bcnt    = (int*)(ws + OFF_BCNT);
    int*    ctr     = bcnt + 10;                    // counters (zeroed)
    float*  spart   = (float*)(ws + OFF_SPART);
    int*    nbr     = (int*)(ws + OFF_NBR);         // zeroed padded nbr table
    int*    row_ptr = (int*)(ws + OFF_ROWPTR);
    int*    blksum  = (int*)(ws + OFF_BLKSUM);
    int*    col     = (int*)(ws + OFF_COL);
    int*    nslot   = (int*)(ws + OFF_NSLOT);
    int*    blist   = (int*)(ws + OFF_BLIST);
    float*  afc     = (float*)(ws + OFF_AFC);
    float*  bng2    = (float*)(ws + OFF_BNG2);
    int*    pblk    = (int*)(ws + OFF_PBLK);        // 11 pblk + 10 ebase
    unsigned short* Fb = (unsigned short*)(ws + OFF_FB);
    unsigned short* Z0 = (unsigned short*)(ws + OFF_Z0);
    unsigned short* Z1 = (unsigned short*)(ws + OFF_Z1);
    unsigned short* Z2 = Z0;   // layer2 output reuses Z0
    unsigned short* WngF = (unsigned short*)(ws + OFF_WNGF);  // in Z1 (free)
    unsigned short* WtrF = (unsigned short*)(ws + OFF_WTRF);  // in Z1 (free)

    hipMemsetAsync(d_ws, 0, ZERO_BYTES, stream);

    k_cast<<<NN * FST / 256, 256, 0, stream>>>(feats, Fb, dst, degcnt);
    k_scan1<<<157, 1024, 0, stream>>>(degcnt, row_ptr, blksum);
    k_scan2<<<1, 256, 0, stream>>>(blksum, 157);
    k_scan3<<<157, 1024, 0, stream>>>(row_ptr, blksum);
    k_bucket<<<157, 1024, 0, stream>>>(degcnt, row_ptr, bcnt, blist, nslot, pblk, ctr);
    k_fill<<<NE / 256, 256, 0, stream>>>(src, dst, row_ptr, cursor, col, nslot, pblk + 11, nbr);

    k_layer<74, FST, false><<<LGRID, 512, 0, stream>>>(
        Fb, nullptr, row_ptr, col, bcnt, blist, pblk, nbr, W0, b0, Z0, spart);
    k_bn<<<63, 256, 0, stream>>>(spart, g0, be0, afc);
    k_layer<63, ZST, true><<<LGRID, 512, 0, stream>>>(
        Z0, afc, row_ptr, col, bcnt, blist, pblk, nbr, W1, b1, Z1, spart + 256 * 128);
    k_bn<<<63, 256, 0, stream>>>(spart + 256 * 128, g1, be1, afc + 128);
    k_layer<63, ZST, true><<<LGRID, 512, 0, stream>>>(
        Z1, afc + 128, row_ptr, col, bcnt, blist, pblk, nbr, W2, b2, Z2, spart + 2 * 256 * 128);
    k_bn<<<63, 256, 0, stream>>>(spart + 2 * 256 * 128, g2, be2, afc + 256);

    // prep fragments (Z1 region is dead after layer2 consumed it)
    k_prepw<<<321, 256, 0, stream>>>(Wng, bng, afc + 256, Wtr, WngF, WtrF, bng2);
    k_graph<<<NG / 16, 256, 0, stream>>>(Z2, WngF, bng2, WtrF, btr, out);
}

// Round 14
// 415.516 us; speedup vs baseline: 1.0327x; 1.0306x over previous
//
#include <hip/hip_runtime.h>
#include <stdint.h>
#include <math.h>

// ---------------- problem constants ----------------
static constexpr int NN = 160000;   // nodes
static constexpr int NE = 640000;   // edges
static constexpr int NG = 8000;     // graphs (20 nodes each, contiguous)
static constexpr int FH  = 63;      // hidden
static constexpr int ZST = 64;      // bf16 elems per Z row (128 B)
static constexpr int FST = 80;      // bf16 elems per feats row (160 B)
static constexpr int NB  = 128;     // nodes per block (8 waves x 8 x 2 iters)
static constexpr int LGRID = 1536;  // >= sum_k ceil(cnt_k/NB) <= ~1260

// ---------------- workspace layout (bytes) ----------------
static constexpr size_t OFF_DEGCNT = 0;                       // 160000 i32
static constexpr size_t OFF_CURSOR = 640000;                  // 160000 i32
static constexpr size_t OFF_BCNT   = 1280000;                 // 16 i32 (10 bcnt + ctrs)
static constexpr size_t OFF_SPART  = 1280064;                 // 3*256*128 f32
static constexpr size_t ZERO_BYTES = 1673280;                 // everything above zeroed
static constexpr size_t OFF_ROWPTR = 1673280;                 // 160001 i32 (final)
static constexpr size_t OFF_ROWPTRP= 2313472;                 // 160001 i32 (partial)
static constexpr size_t OFF_BLKSUM = 2953728;                 // 512 i32
static constexpr size_t OFF_COL    = 2955776;                 // 640000 i32
static constexpr size_t OFF_BLIST  = 5515776;                 // 10*160000 int2 (n, row_start)
static constexpr size_t OFF_AFC    = 18315776;                // 3*2*64 f32
static constexpr size_t OFF_BNG2   = 18316544;                // 128 f32
static constexpr size_t OFF_PBLK   = 18317056;                // 11 i32
static constexpr size_t OFF_FB     = 18317184;                // 160000*80 bf16 (feats cast)
static constexpr size_t OFF_Z0     = 43917184;                // 160000*64 bf16
static constexpr size_t OFF_Z1     = 64397184;                // 160000*64 bf16 (free after layer2)
// Z1 region reused after layer2 for the readout weight fragments:
static constexpr size_t OFF_WNGF   = OFF_Z1;                  // 32 KB
static constexpr size_t OFF_WTRF   = OFF_Z1 + 32768;          // 128 KB
// total ~84.9 MB

// ---------------- bf16 helpers ----------------
__device__ __forceinline__ float blo(unsigned u) {
    union { unsigned i; float f; } v; v.i = u << 16; return v.f;
}
__device__ __forceinline__ float bhi(unsigned u) {
    union { unsigned i; float f; } v; v.i = u & 0xffff0000u; return v.f;
}
__device__ __forceinline__ unsigned short f2b(float f) {
    union { float f; unsigned i; } v; v.f = f;
    unsigned r = v.i + 0x7fffu + ((v.i >> 16) & 1u);
    return (unsigned short)(r >> 16);
}
// accumulate 8 bf16 (one uint4) into 8 f32
__device__ __forceinline__ void acc8(float* a, uint4 q) {
    a[0] += blo(q.x); a[1] += bhi(q.x);
    a[2] += blo(q.y); a[3] += bhi(q.y);
    a[4] += blo(q.z); a[5] += bhi(q.z);
    a[6] += blo(q.w); a[7] += bhi(q.w);
}

// ---------------- MFMA types ----------------
typedef __attribute__((ext_vector_type(8))) short bf16x8;
typedef __attribute__((ext_vector_type(4))) float f32x4;
union U8 { uint4 u; bf16x8 b; };

// ---------------- fused cast + degree ----------------
// feats f32 [NN][74] -> bf16 [NN][80] (padded with zeros); first NE threads
// also do the degree histogram (independent work, saves a serial launch).
__global__ void k_cast(const float* __restrict__ feats, unsigned short* __restrict__ fb,
                       const int* __restrict__ dst, int* __restrict__ degcnt) {
    int i = blockIdx.x * 256 + threadIdx.x;
    if (i < NE) atomicAdd(&degcnt[dst[i]], 1);
    if (i >= NN * FST) return;
    int n = i / FST, c = i - n * FST;
    float v = (c < 74) ? feats[n * 74 + c] : 0.f;
    union { float f; unsigned u; } x; x.f = v;
    unsigned r = x.u + 0x7fffu + ((x.u >> 16) & 1u);
    fb[i] = (unsigned short)(r >> 16);
}

// ---------------- fused scan: per-block inclusive scan + last-block blksum scan ----------------
// Writes row_ptrP[i+1] = local inclusive prefix; blksum[b] = block total, then
// the LAST-finishing block converts blksum to an exclusive prefix in place.
// (Removes the old 1-block k_scan2 — a pure pipeline bubble.)
__global__ void __launch_bounds__(1024) k_scan1(
        const int* __restrict__ degcnt, int* __restrict__ row_ptrP,
        int* __restrict__ blksum, int* __restrict__ ctr) {
    __shared__ int s[1024];
    __shared__ int sLast;
    int t = threadIdx.x;
    int i = blockIdx.x * 1024 + t;
    int v = (i < NN) ? degcnt[i] : 0;
    s[t] = v; __syncthreads();
    for (int off = 1; off < 1024; off <<= 1) {
        int x = (t >= off) ? s[t - off] : 0;
        __syncthreads();
        s[t] += x;
        __syncthreads();
    }
    if (i < NN) row_ptrP[i + 1] = s[t];
    if (t == 1023) blksum[blockIdx.x] = s[t];

    if (t == 0) {
        __threadfence();
        sLast = (atomicAdd(ctr, 1) == (int)gridDim.x - 1) ? 1 : 0;
    }
    __syncthreads();
    if (sLast) {
        __threadfence();
        int vv = 0;
        if (t < 256) {
            const volatile int* bs = blksum;
            vv = (t < 157) ? bs[t] : 0;
            s[t] = vv;
        }
        __syncthreads();
        for (int off = 1; off < 256; off <<= 1) {
            int x = (t >= off && t < 256) ? s[t - off] : 0;
            __syncthreads();
            if (t < 256) s[t] += x;
            __syncthreads();
        }
        if (t < 157) blksum[t] = s[t] - vv;   // exclusive prefix
    }
}

// ---------------- fused row_ptr finalize + bucket build + CSR fill ----------------
// Roles by blockIdx: [0,157) bucket-role over nodes (finalize row_ptr into a
// SEPARATE array — no race with fill-role readers of row_ptrP — and build
// blist/bcnt; last finisher computes pblk). [157, 782) fill-role over edges,
// computing each dst row offset from row_ptrP + blksum directly.
__global__ void __launch_bounds__(1024) k_buckfill(
        const int* __restrict__ degcnt, const int* __restrict__ row_ptrP,
        const int* __restrict__ blksum, int* __restrict__ row_ptr,
        int* __restrict__ bcnt, int2* __restrict__ blist,
        const int* __restrict__ src, const int* __restrict__ dst,
        int* __restrict__ cursor, int* __restrict__ col,
        int* __restrict__ pblk, int* __restrict__ ctr) {
    int bid = blockIdx.x, tid = threadIdx.x;
    if (bid < 157) {
        __shared__ int scnt[10], sbase[10];
        __shared__ int sLast;
        if (tid < 10) scnt[tid] = 0;
        __syncthreads();
        int n = bid * 1024 + tid;
        bool v = (n < NN);
        int k = 0, pos = 0, rp = 0;
        if (v) {
            int d = degcnt[n];
            k = (d < 1) ? 0 : ((d > 10) ? 9 : d - 1);
            pos = atomicAdd(&scnt[k], 1);
            rp = (n == 0) ? 0 : (row_ptrP[n] + blksum[(n - 1) >> 10]);
            row_ptr[n + 1] = row_ptrP[n + 1] + blksum[n >> 10];
            if (n == 0) row_ptr[0] = 0;
        }
        __syncthreads();
        if (tid < 10) sbase[tid] = scnt[tid] ? atomicAdd(&bcnt[tid], scnt[tid]) : 0;
        __syncthreads();
        if (v) blist[k * NN + sbase[k] + pos] = make_int2(n, rp);

        if (tid == 0) {
            __threadfence();
            sLast = (atomicAdd(ctr, 1) == 156) ? 1 : 0;
        }
        __syncthreads();
        if (sLast && tid == 0) {
            __threadfence();
            const volatile int* bc = bcnt;
            int s = 0; pblk[0] = 0;
            for (int kk = 0; kk < 10; ++kk) { s += (bc[kk] + NB - 1) / NB; pblk[kk + 1] = s; }
        }
    } else {
        int e = (bid - 157) * 1024 + tid;
        if (e >= NE) return;
        int d = dst[e];
        int rpd = (d == 0) ? 0 : (row_ptrP[d] + blksum[(d - 1) >> 10]);
        int pos = rpd + atomicAdd(&cursor[d], 1);
        col[pos] = src[e];
    }
}

// ---------------- NF layer: degree-generic gather, 128 nodes/block, 8 waves ----------------
// SEVEN gather structures (R2/R3/R4/R10/R11/R12/R13) all land at 73-83us and
// ~1.6 TB/s: per-CU scattered-read throughput is capped (~18 outstanding
// 128B lines/CU at ~900cy => 2.6 B/cy/CU), independent of ILP or occupancy.
// This is the proven R9 body (VGPR 40-44) — the floor. DO NOT restructure.
template<int FI, int IST, bool AFF>
__global__ void __launch_bounds__(512, 4) k_layer(
    const unsigned short* __restrict__ in,
    const float* __restrict__ aff,
    const int* __restrict__ row_ptr, const int* __restrict__ col,
    const int* __restrict__ bcnt, const int2* __restrict__ blist,
    const int* __restrict__ pblk,
    const float* __restrict__ W, const float* __restrict__ B,
    unsigned short* __restrict__ zout, float* __restrict__ spart)
{
    constexpr int CH = IST / 8;      // uint4 chunks per row (64->8, 80->10)
    __shared__ float sW[FI * 63 + 64];
    __shared__ float sTot[8][IST][8];
    __shared__ int   sN[8][8];
    __shared__ float sRed[2][8][64];

    int b = blockIdx.x;
    if (b >= pblk[10]) return;
    int k = 0;
#pragma unroll
    for (int i = 1; i <= 9; ++i) k += (b >= pblk[i]) ? 1 : 0;   // uniform (sgpr)
    int base = (b - pblk[k]) * NB;
    int cnt = bcnt[k];
    if (base >= cnt) return;

    int tid = threadIdx.x;
    int wave = tid >> 6, lane = tid & 63;
    int t = lane >> 3, r = lane & 7;

    const float* Wk = W + (size_t)k * FI * 63;
#pragma unroll 4
    for (int i = tid; i < FI * 63; i += 512) sW[i] = Wk[i];
    __syncthreads();

    const uint4* inq = (const uint4*)in;
    float bterm = (lane < 63) ? B[k * 63 + lane] : 0.f;
    float lsum = 0.f, lsq = 0.f;

#pragma unroll 1
    for (int it = 0; it < NB / 64; ++it) {
        int idx = base + it * 64 + wave * 8 + t;
        if (base + it * 64 >= cnt) break;                 // whole-batch empty (uniform)
        bool val = (idx < cnt);
        int2 bl = blist[k * NN + (val ? idx : (cnt - 1))];
        int n = bl.x, rs = bl.y;
        // buckets 1..8: deg == k+1 exactly (uniform). 0 and 9: per-node.
        int dg = (k >= 1 && k <= 8) ? (k + 1) : (row_ptr[n + 1] - rs);
        if (r == 0) sN[wave][t] = val ? n : -1;

        float a[8] = {0.f, 0.f, 0.f, 0.f, 0.f, 0.f, 0.f, 0.f};
        {   // self row (main 8 chunks)
            uint4 q = inq[(size_t)n * CH + r];
            acc8(a, q);
        }
        // neighbor rows: 4 in flight/iter; trip wave-uniform (1..8) or masked.
        int d = 0;
#pragma unroll 1
        for (; d + 4 <= dg; d += 4) {
            int c0 = col[rs + d], c1 = col[rs + d + 1];
            int c2 = col[rs + d + 2], c3 = col[rs + d + 3];
            uint4 q0 = inq[(size_t)c0 * CH + r];
            uint4 q1 = inq[(size_t)c1 * CH + r];
            uint4 q2 = inq[(size_t)c2 * CH + r];
            uint4 q3 = inq[(size_t)c3 * CH + r];
            acc8(a, q0); acc8(a, q1); acc8(a, q2); acc8(a, q3);
        }
#pragma unroll 1
        for (; d < dg; ++d) {
            int c = col[rs + d];
            uint4 q = inq[(size_t)c * CH + r];
            acc8(a, q);
        }

        // layer-0 extra chunks (feats bytes 128..159): r<2 lanes only
        if constexpr (IST == 80) {
            float e2[8] = {0.f, 0.f, 0.f, 0.f, 0.f, 0.f, 0.f, 0.f};
            if (r < 2) {
                uint4 q = inq[(size_t)n * CH + 8 + r];
                acc8(e2, q);
                int d2 = 0;
#pragma unroll 1
                for (; d2 < dg; ++d2) {
                    int c = col[rs + d2];
                    uint4 p = inq[(size_t)c * CH + 8 + r];
                    acc8(e2, p);
                }
#pragma unroll
                for (int j = 0; j < 8; ++j) sTot[wave][64 + 8 * r + j][t] = e2[j];
            }
        }

        if constexpr (AFF) {
            // tot = a_bn*(y_self + sum y_nb) + (deg+1)*c_bn, feats 8r..8r+7
            const float4* af = (const float4*)aff;
            float4 A0 = af[2 * r], A1 = af[2 * r + 1];
            float4 C0 = af[16 + 2 * r], C1 = af[16 + 2 * r + 1];
            float dp1 = (float)(dg + 1);
            a[0] = A0.x * a[0] + dp1 * C0.x;  a[1] = A0.y * a[1] + dp1 * C0.y;
            a[2] = A0.z * a[2] + dp1 * C0.z;  a[3] = A0.w * a[3] + dp1 * C0.w;
            a[4] = A1.x * a[4] + dp1 * C1.x;  a[5] = A1.y * a[5] + dp1 * C1.y;
            a[6] = A1.z * a[6] + dp1 * C1.z;  a[7] = A1.w * a[7] + dp1 * C1.w;
        }

        // transpose through LDS: sTot[wave][feat][node] (same-wave, no barrier)
#pragma unroll
        for (int j = 0; j < 8; ++j) sTot[wave][8 * r + j][t] = a[j];

        // matmul: lane = output o; 8 nodes per wave. unroll 4 = bounded liveness.
        float acc[8];
#pragma unroll
        for (int i = 0; i < 8; ++i) acc[i] = bterm;
#pragma unroll 4
        for (int j = 0; j < FI; ++j) {
            float w = sW[j * 63 + lane];   // lane 63 reads pad garbage; unused
            float4 u = *(const float4*)&sTot[wave][j][0];
            float4 v = *(const float4*)&sTot[wave][j][4];
            acc[0] = fmaf(u.x, w, acc[0]); acc[1] = fmaf(u.y, w, acc[1]);
            acc[2] = fmaf(u.z, w, acc[2]); acc[3] = fmaf(u.w, w, acc[3]);
            acc[4] = fmaf(v.x, w, acc[4]); acc[5] = fmaf(v.y, w, acc[5]);
            acc[6] = fmaf(v.z, w, acc[6]); acc[7] = fmaf(v.w, w, acc[7]);
        }

        // relu, store, accumulate per-lane stats
#pragma unroll
        for (int tt = 0; tt < 8; ++tt) {
            int nn = sN[wave][tt];
            float z = fmaxf(acc[tt], 0.f);
            if (nn >= 0 && lane < 63) {
                zout[(size_t)nn * ZST + lane] = f2b(z);
                lsum += z; lsq += z * z;
            }
        }
    }

    sRed[0][wave][lane] = lsum;
    sRed[1][wave][lane] = lsq;
    __syncthreads();
    if (wave == 0 && lane < 63) {
        float s = 0.f, q = 0.f;
#pragma unroll
        for (int w8 = 0; w8 < 8; ++w8) {
            s += sRed[0][w8][lane];
            q += sRed[1][w8][lane];
        }
        float* sp = spart + (size_t)(blockIdx.x & 255) * 128;
        atomicAdd(&sp[lane], s);
        atomicAdd(&sp[64 + lane], q);
    }
}

// ---------------- BN stats -> affine (a, c), parallel ----------------
__global__ void k_bn(const float* __restrict__ spart, const float* __restrict__ gamma,
                     const float* __restrict__ beta, float* __restrict__ afc) {
    __shared__ double sd[512];
    int o = blockIdx.x;            // 0..62
    int t = threadIdx.x;           // cp 0..255
    sd[t]       = (double)spart[t * 128 + o];
    sd[256 + t] = (double)spart[t * 128 + 64 + o];
    __syncthreads();
#pragma unroll
    for (int off = 128; off > 0; off >>= 1) {
        if (t < off) { sd[t] += sd[t + off]; sd[256 + t] += sd[256 + t + off]; }
        __syncthreads();
    }
    if (t == 0) {
        double mu  = sd[0] / NN;
        double var = sd[256] / NN - mu * mu;
        float a = (float)((double)gamma[o] / sqrt(var + 1e-5));
        float c = (float)((double)beta[o] - mu * (double)a);
        afc[o] = a;
        afc[64 + o] = c;
    }
}

// ---------------- prep for MFMA readout ----------------
__global__ void k_prepw(const float* __restrict__ W_ng, const float* __restrict__ b_ng,
                        const float* __restrict__ afc2, const float* __restrict__ W_tr,
                        unsigned short* __restrict__ WngF, unsigned short* __restrict__ WtrF,
                        float* __restrict__ bng2) {
    int bid = blockIdx.x, tid = threadIdx.x;
    if (bid == 0) {
        if (tid < 128) {
            float acc = b_ng[tid];
            for (int j = 0; j < 63; ++j)
                acc = fmaf(afc2[64 + j], W_ng[j * 128 + tid], acc);
            bng2[tid] = acc;
        }
    } else if (bid <= 64) {
        int idx = (bid - 1) * 256 + tid;          // [0,16384)
        int j = idx & 7, lane = (idx >> 3) & 63;
        int nt = (idx >> 9) & 7, kb = idx >> 12;  // kb 0..3
        int k = (kb & 1) * 32 + ((lane >> 4) << 3) + j;
        int col = nt * 16 + (lane & 15);
        float w = (k < 63) ? afc2[k] * W_ng[k * 128 + col] : 0.f;
        unsigned short hi = f2b(w);
        if (kb < 2) WngF[idx] = hi;
        else        WngF[idx] = f2b(w - blo(hi));
    } else {
        int idx = (bid - 65) * 256 + tid;         // [0,65536)
        int j = idx & 7, lane = (idx >> 3) & 63;
        int kb = (idx >> 9) & 7, nt = idx >> 12;  // nt 0..15
        int k = kb * 32 + ((lane >> 4) << 3) + j;
        int col = nt * 16 + (lane & 15);
        WtrF[idx] = f2b(W_tr[k * 256 + col]);
    }
}

// ---------------- readout: MFMA over both GEMMs ----------------
__global__ void __launch_bounds__(256, 2) k_graph(
    const unsigned short* __restrict__ Z2, const unsigned short* __restrict__ WngF,
    const float* __restrict__ bng2, const unsigned short* __restrict__ WtrF,
    const float* __restrict__ b_tr, float* __restrict__ out)
{
    __shared__ unsigned short sW[16384];     // 32 KB WngF frags
    __shared__ float sT[16 * 256];           // 16 KB tanh'd readout, swizzled
    __shared__ float sB[128];                // bng2

    int tid = threadIdx.x;
    int wave = tid >> 6, lane = tid & 63;
    int gl15 = lane & 15, grp = lane >> 4;

    // stage WngF (2048 uint4) + bng2
    {
        const uint4* srcq = (const uint4*)WngF;
        uint4* dstq = (uint4*)sW;
#pragma unroll
        for (int i = 0; i < 8; ++i) dstq[tid + 256 * i] = srcq[tid + 256 * i];
    }
    if (tid < 128) sB[tid] = bng2[tid];
    __syncthreads();

    // A-fragments: 5 M-tiles x (k0-31, k32-63). Lane l holds node (l&15),
    // k-slots (l>>4)*8.. — one contiguous uint4 of the Z row each.
    int nodeBase = blockIdx.x * 320 + wave * 80;
    const uint4* zq = (const uint4*)Z2;      // 8 uint4 per 64-bf16 row
    uint4 a0[5], a1[5];
#pragma unroll
    for (int m = 0; m < 5; ++m) {
        size_t row = (size_t)(nodeBase + m * 16 + gl15) * 8;
        a0[m] = zq[row + grp];
        a1[m] = zq[row + 4 + grp];
    }
    if (grp == 3) {                          // k=63 is pad (poison): zero it
#pragma unroll
        for (int m = 0; m < 5; ++m) a1[m].w &= 0xffffu;
    }

    const uint4* swq = (const uint4*)sW;
    const float NEGI = -3.0e38f;

#pragma unroll 1
    for (int nt = 0; nt < 8; ++nt) {
        U8 b0, b1, b2, b3;                   // kblk 0..3 (hi,hi,lo,lo)
        b0.u = swq[(0 * 8 + nt) * 64 + lane];
        b1.u = swq[(1 * 8 + nt) * 64 + lane];
        b2.u = swq[(2 * 8 + nt) * 64 + lane];
        b3.u = swq[(3 * 8 + nt) * 64 + lane];

        f32x4 ac[5];
#pragma unroll
        for (int m = 0; m < 5; ++m) {
            U8 xa0, xa1; xa0.u = a0[m]; xa1.u = a1[m];
            f32x4 c = {0.f, 0.f, 0.f, 0.f};
            c = __builtin_amdgcn_mfma_f32_16x16x32_bf16(xa0.b, b0.b, c, 0, 0, 0);
            c = __builtin_amdgcn_mfma_f32_16x16x32_bf16(xa1.b, b1.b, c, 0, 0, 0);
            c = __builtin_amdgcn_mfma_f32_16x16x32_bf16(xa0.b, b2.b, c, 0, 0, 0);
            c = __builtin_amdgcn_mfma_f32_16x16x32_bf16(xa1.b, b3.b, c, 0, 0, 0);
            ac[m] = c;
        }

        // fold rows into the wave's 4 graphs. wave-local row = m*16 + grp*4 + r.
        float s[4] = {0.f, 0.f, 0.f, 0.f};
        float x[4] = {NEGI, NEGI, NEGI, NEGI};
        bool cA = lane < 16, cB = lane < 32, cC = lane < 48;
#pragma unroll
        for (int r = 0; r < 4; ++r) {
            float v0 = ac[0][r]; s[0] += v0; x[0] = fmaxf(x[0], v0);
            float v4 = ac[4][r]; s[3] += v4; x[3] = fmaxf(x[3], v4);
            float v1 = ac[1][r]; float v1a = cA ? v1 : 0.f;
            s[0] += v1a; s[1] += v1 - v1a;
            x[0] = fmaxf(x[0], cA ? v1 : NEGI); x[1] = fmaxf(x[1], cA ? NEGI : v1);
            float v2 = ac[2][r]; float v2a = cB ? v2 : 0.f;
            s[1] += v2a; s[2] += v2 - v2a;
            x[1] = fmaxf(x[1], cB ? v2 : NEGI); x[2] = fmaxf(x[2], cB ? NEGI : v2);
            float v3 = ac[3][r]; float v3a = cC ? v3 : 0.f;
            s[2] += v3a; s[3] += v3 - v3a;
            x[2] = fmaxf(x[2], cC ? v3 : NEGI); x[3] = fmaxf(x[3], cC ? NEGI : v3);
        }
        // butterfly over the 4 lane groups (row partials live 16 lanes apart)
#pragma unroll
        for (int g = 0; g < 4; ++g) {
            s[g] += __shfl_xor(s[g], 16);
            s[g] += __shfl_xor(s[g], 32);
            x[g] = fmaxf(x[g], __shfl_xor(x[g], 16));
            x[g] = fmaxf(x[g], __shfl_xor(x[g], 32));
        }
        if (lane < 16) {
            int c = nt * 16 + lane;
            float bb = sB[c];
#pragma unroll
            for (int g = 0; g < 4; ++g) {
                int row = wave * 4 + g;
                int swz = (row & 7) << 2;
                sT[(row * 256 + c) ^ swz]       = tanhf(s[g] + 20.f * bb);
                sT[(row * 256 + 128 + c) ^ swz] = tanhf(x[g] + bb);
            }
        }
    }
    __syncthreads();

    // phase B: out[16 x 256] = T @ W_tr, K=256.
    U8 pa[8];
    {
        int swz = (gl15 & 7) << 2;
#pragma unroll
        for (int kb = 0; kb < 8; ++kb) {
            int k8 = kb * 32 + grp * 8;
            float4 t0 = *(const float4*)&sT[(gl15 * 256 + k8) ^ swz];
            float4 t1 = *(const float4*)&sT[(gl15 * 256 + k8 + 4) ^ swz];
            unsigned u0 = (unsigned)f2b(t0.x) | ((unsigned)f2b(t0.y) << 16);
            unsigned u1 = (unsigned)f2b(t0.z) | ((unsigned)f2b(t0.w) << 16);
            unsigned u2 = (unsigned)f2b(t1.x) | ((unsigned)f2b(t1.y) << 16);
            unsigned u3 = (unsigned)f2b(t1.z) | ((unsigned)f2b(t1.w) << 16);
            pa[kb].u = make_uint4(u0, u1, u2, u3);
        }
    }
    const uint4* wtq = (const uint4*)WtrF;
    size_t gbase = (size_t)blockIdx.x * 16 * 256;
#pragma unroll 2
    for (int i = 0; i < 4; ++i) {
        int nt = wave * 4 + i;
        f32x4 c = {0.f, 0.f, 0.f, 0.f};
#pragma unroll
        for (int kb = 0; kb < 8; ++kb) {
            U8 b; b.u = wtq[(nt * 8 + kb) * 64 + lane];
            c = __builtin_amdgcn_mfma_f32_16x16x32_bf16(pa[kb].b, b.b, c, 0, 0, 0);
        }
        int d = nt * 16 + gl15;
        float btv = b_tr[d];
#pragma unroll
        for (int r = 0; r < 4; ++r) {
            int row = grp * 4 + r;           // graph within block
            out[gbase + (size_t)row * 256 + d] = c[r] + btv;
        }
    }
}

// ---------------- launch ----------------
extern "C" void kernel_launch(void* const* d_in, const int* in_sizes, int n_in,
                              void* d_out, int out_size, void* d_ws, size_t ws_size,
                              hipStream_t stream) {
    const float* feats = (const float*)d_in[0];
    const int*   src   = (const int*)d_in[1];
    const int*   dst   = (const int*)d_in[2];
    // d_in[3] = graph_ids: repeat(arange(8000), 20) -> node/20, unused
    const float* W0 = (const float*)d_in[4];
    const float* b0 = (const float*)d_in[5];
    const float* g0 = (const float*)d_in[6];
    const float* be0 = (const float*)d_in[7];
    const float* W1 = (const float*)d_in[8];
    const float* b1 = (const float*)d_in[9];
    const float* g1 = (const float*)d_in[10];
    const float* be1 = (const float*)d_in[11];
    const float* W2 = (const float*)d_in[12];
    const float* b2 = (const float*)d_in[13];
    const float* g2 = (const float*)d_in[14];
    const float* be2 = (const float*)d_in[15];
    const float* Wng = (const float*)d_in[16];
    const float* bng = (const float*)d_in[17];
    const float* Wtr = (const float*)d_in[18];
    const float* btr = (const float*)d_in[19];
    float* out = (float*)d_out;

    char* ws = (char*)d_ws;
    int*    degcnt  = (int*)(ws + OFF_DEGCNT);
    int*    cursor  = (int*)(ws + OFF_CURSOR);
    int*    bcnt    = (int*)(ws + OFF_BCNT);
    int*    ctr     = bcnt + 10;                    // counters (zeroed)
    float*  spart   = (float*)(ws + OFF_SPART);
    int*    row_ptr = (int*)(ws + OFF_ROWPTR);
    int*    row_ptrP= (int*)(ws + OFF_ROWPTRP);
    int*    blksum  = (int*)(ws + OFF_BLKSUM);
    int*    col     = (int*)(ws + OFF_COL);
    int2*   blist   = (int2*)(ws + OFF_BLIST);
    float*  afc     = (float*)(ws + OFF_AFC);
    float*  bng2    = (float*)(ws + OFF_BNG2);
    int*    pblk    = (int*)(ws + OFF_PBLK);
    unsigned short* Fb = (unsigned short*)(ws + OFF_FB);
    unsigned short* Z0 = (unsigned short*)(ws + OFF_Z0);
    unsigned short* Z1 = (unsigned short*)(ws + OFF_Z1);
    unsigned short* Z2 = Z0;   // layer2 output reuses Z0
    unsigned short* WngF = (unsigned short*)(ws + OFF_WNGF);  // in Z1 (free)
    unsigned short* WtrF = (unsigned short*)(ws + OFF_WTRF);  // in Z1 (free)

    hipMemsetAsync(d_ws, 0, ZERO_BYTES, stream);

    k_cast<<<NN * FST / 256, 256, 0, stream>>>(feats, Fb, dst, degcnt);
    k_scan1<<<157, 1024, 0, stream>>>(degcnt, row_ptrP, blksum, ctr + 0);
    k_buckfill<<<782, 1024, 0, stream>>>(degcnt, row_ptrP, blksum, row_ptr,
                                         bcnt, blist, src, dst, cursor, col,
                                         pblk, ctr + 1);

    k_layer<74, FST, false><<<LGRID, 512, 0, stream>>>(
        Fb, nullptr, row_ptr, col, bcnt, blist, pblk, W0, b0, Z0, spart);
    k_bn<<<63, 256, 0, stream>>>(spart, g0, be0, afc);
    k_layer<63, ZST, true><<<LGRID, 512, 0, stream>>>(
        Z0, afc, row_ptr, col, bcnt, blist, pblk, W1, b1, Z1, spart + 256 * 128);
    k_bn<<<63, 256, 0, stream>>>(spart + 256 * 128, g1, be1, afc + 128);
    k_layer<63, ZST, true><<<LGRID, 512, 0, stream>>>(
        Z1, afc + 128, row_ptr, col, bcnt, blist, pblk, W2, b2, Z2, spart + 2 * 256 * 128);
    k_bn<<<63, 256, 0, stream>>>(spart + 2 * 256 * 128, g2, be2, afc + 256);

    // prep fragments (Z1 region is dead after layer2 consumed it)
    k_prepw<<<321, 256, 0, stream>>>(Wng, bng, afc + 256, Wtr, WngF, WtrF, bng2);
    k_graph<<<NG / 16, 256, 0, stream>>>(Z2, WngF, bng2, WtrF, btr, out);
}